// Round 12
// baseline (825.850 us; speedup 1.0000x reference)
//
#include <hip/hip_runtime.h>
#include <hip/hip_bf16.h>
#include <math.h>

#define N_NODES 50000
#define N_EDGES 800000
#define N_GRAPHS 64
#define SCAN_BLOCKS 196   // ceil(50000/256)
#define DHB_N (256 * SCAN_BLOCKS)   // 50176
#define NCH1 782          // ceil(50000/64)  edge1 chunks (64 nodes)
#define NCH2 391          // ceil(50000/128) edge2 chunks (128 nodes)

typedef __attribute__((ext_vector_type(8))) short short8v;   // 8 bf16 (4 VGPRs)
typedef __attribute__((ext_vector_type(4))) float float4v;   // MFMA acc

// ---------------- workspace layout (bytes) ----------------
// Feature tensors are CHANNEL-GROUP-major: [8 groups][50000 nodes][slice];
// group g is processed only by blocks physically on XCD g (HW_REG_XCC_ID)
// via per-group work queues -> per-XCD gather set is L2-resident by construction.
static constexpr size_t OFF_K1   = 0;            // bf16 [8][50000][16]  (pre-scaled -log2e)
static constexpr size_t OFF_S1   = 12800000;     // bf16 [8][50000][16]
static constexpr size_t OFF_QV1  = 25600000;     // u16  [8][50000][32]  (qv interleaved)
static constexpr size_t OFF_H1B  = 51200000;     // bf16 [8][50000][16]
static constexpr size_t OFF_XB   = 64000000;     // bf16 [50000][128]    (row-major)
// layer2 overlays layer1 buffers (K1/S1/QV1 dead after edge1):
static constexpr size_t OFF_K2   = 0;            // bf16 [8][50000][8]   (pre-scaled)
static constexpr size_t OFF_S2   = 6400000;      // bf16 [8][50000][8]
static constexpr size_t OFF_QV2  = 12800000;     // u16  [8][50000][16]
static constexpr size_t OFF_H2   = 25600000;     // f32  [8][50000][8]
static constexpr size_t OFF_ESRC = 76800000;     // 3.2 MB
static constexpr size_t OFF_OFFS = 80000000;     // 50001*4 -> pad
static constexpr size_t OFF_CURS = 80200064;     // 50000*4 (hist, then cursor)
static constexpr size_t OFF_BSUM = 80400064;     // 196*4
static constexpr size_t OFF_BBAS = 80400848;
static constexpr size_t OFF_BP1  = 80401664;     // bf16 packed 128*512
static constexpr size_t OFF_BC1  = 80532736;     // 512*4
static constexpr size_t OFF_BP2  = 80534784;     // bf16 packed 128*256
static constexpr size_t OFF_BC2  = 80600320;     // 256*4
static constexpr size_t OFF_SG   = 80601344;
static constexpr size_t OFF_EG   = 80601600;
static constexpr size_t OFF_PL   = 80601856;     // 64*64*4 -> ends 80618240
static constexpr size_t OFF_PERM = 80620032;     // 50000*4 -> ends 80820032
static constexpr size_t OFF_DHB  = 80820032;     // 50176*4 -> ends 81020736
static constexpr size_t OFF_DSB  = 81020736;     // 50176*4 -> ends 81221440
static constexpr size_t OFF_DB2  = 81221440;     // 196*4
static constexpr size_t OFF_DB3  = 81222464;     // 256*4
static constexpr size_t OFF_QC1  = 81223488;     // 8*4 queue counters (edge1)
static constexpr size_t OFF_QC2  = 81223520;     // 8*4 queue counters (edge2) -- ADJACENT to qc1

#define NLOG2E 1.44269504f   // gate = rcp(1 + exp2(k' + q')), k'/q' pre-scaled by -log2e

__device__ inline unsigned short f2bf(float f) {
    __hip_bfloat16 h = __float2bfloat16(f);
    union { __hip_bfloat16 h; unsigned short u; } cv;
    cv.h = h;
    return cv.u;
}
__device__ inline float fast_exp2(float x) { float r; asm("v_exp_f32 %0, %1" : "=v"(r) : "v"(x)); return r; }
__device__ inline float fast_rcp (float x) { float r; asm("v_rcp_f32 %0, %1" : "=v"(r) : "v"(x)); return r; }
__device__ inline float u2f(unsigned int u) { union { unsigned int i; float f; } w; w.i = u; return w.f; }
__device__ inline int xcc_id() {
    int x;
    asm("s_getreg_b32 %0, hwreg(HW_REG_XCC_ID, 0, 4)" : "=s"(x));
    return x & 7;
}

// qv uint = [q' lo16 | v hi16]; accumulate 4 channels
__device__ inline void gacc4(uint4 qv, float k0, float k1, float k2, float k3, float* a) {
    float q0 = u2f(qv.x << 16), v0 = u2f(qv.x & 0xffff0000u);
    float q1 = u2f(qv.y << 16), v1 = u2f(qv.y & 0xffff0000u);
    float q2 = u2f(qv.z << 16), v2 = u2f(qv.z & 0xffff0000u);
    float q3 = u2f(qv.w << 16), v3 = u2f(qv.w & 0xffff0000u);
    a[0] += v0 * fast_rcp(1.f + fast_exp2(k0 + q0));
    a[1] += v1 * fast_rcp(1.f + fast_exp2(k1 + q1));
    a[2] += v2 * fast_rcp(1.f + fast_exp2(k2 + q2));
    a[3] += v3 * fast_rcp(1.f + fast_exp2(k3 + q3));
}

// ---------------- x -> bf16 cast ----------------
__global__ void cast_kernel(const float* __restrict__ x, unsigned short* __restrict__ xb) {
    int id = blockIdx.x * 256 + threadIdx.x;
    float4 v0 = *(const float4*)&x[(size_t)id * 8];
    float4 v1 = *(const float4*)&x[(size_t)id * 8 + 4];
    short8v o;
    o[0] = (short)f2bf(v0.x); o[1] = (short)f2bf(v0.y);
    o[2] = (short)f2bf(v0.z); o[3] = (short)f2bf(v0.w);
    o[4] = (short)f2bf(v1.x); o[5] = (short)f2bf(v1.y);
    o[6] = (short)f2bf(v1.z); o[7] = (short)f2bf(v1.w);
    *(short8v*)(xb + (size_t)id * 8) = o;
}

// ---------------- weight prep: pack into MFMA B-fragment order ----------------
__global__ void prep1_kernel(const float* __restrict__ wk, const float* __restrict__ bk,
                             const float* __restrict__ wq, const float* __restrict__ bq,
                             const float* __restrict__ wv, const float* __restrict__ bv,
                             const float* __restrict__ ws, const float* __restrict__ bs,
                             unsigned short* __restrict__ Bp, float* __restrict__ bcat) {
    int id = blockIdx.x * 256 + threadIdx.x;      // 8192 total
    if (id < 8192) {
        int l = id & 63, ks = (id >> 6) & 3, ct = id >> 8;
        int c = ct * 16 + (l & 15);
        int g = c >> 7, n = c & 127;
        const float* W = (g == 0) ? wk : (g == 1) ? wq : (g == 2) ? wv : ws;
        int kb = ks * 32 + ((l >> 4) << 3);
        short8v o;
#pragma unroll
        for (int j = 0; j < 8; ++j) o[j] = (short)f2bf(W[n * 128 + kb + j]);
        *(short8v*)(Bp + (size_t)id * 8) = o;
    }
    if (id < 512) {
        int g = id >> 7, n = id & 127;
        const float* B = (g == 0) ? bk : (g == 1) ? bq : (g == 2) ? bv : bs;
        bcat[id] = B[n];
    }
}

__global__ void prep2_kernel(const float* __restrict__ wk, const float* __restrict__ bk,
                             const float* __restrict__ wq, const float* __restrict__ bq,
                             const float* __restrict__ wv, const float* __restrict__ bv,
                             const float* __restrict__ ws, const float* __restrict__ bs,
                             unsigned short* __restrict__ Bp, float* __restrict__ bcat) {
    int id = blockIdx.x * 256 + threadIdx.x;      // 4096 total
    if (id < 4096) {
        int l = id & 63, ks = (id >> 6) & 3, ct = id >> 8;
        int c = ct * 16 + (l & 15);
        int g = c >> 6, n = c & 63;
        const float* W = (g == 0) ? wk : (g == 1) ? wq : (g == 2) ? wv : ws;
        int kb = ks * 32 + ((l >> 4) << 3);
        short8v o;
#pragma unroll
        for (int j = 0; j < 8; ++j) o[j] = (short)f2bf(W[n * 128 + kb + j]);
        *(short8v*)(Bp + (size_t)id * 8) = o;
    }
    if (id < 256) {
        int g = id >> 6, n = id & 63;
        const float* B = (g == 0) ? bk : (g == 1) ? bq : (g == 2) ? bv : bs;
        bcat[id] = B[n];
    }
}

// ---------------- CSR build ----------------
__global__ void hist_kernel(const int* __restrict__ dst, int* __restrict__ hist) {
    int e = blockIdx.x * 256 + threadIdx.x;
    if (e < N_EDGES) atomicAdd(&hist[dst[e]], 1);
}

__global__ void bsum_kernel(const int* __restrict__ hist, int* __restrict__ bsum, int n) {
    int t = threadIdx.x;
    int idx = blockIdx.x * 256 + t;
    __shared__ int sh[256];
    sh[t] = (idx < n) ? hist[idx] : 0;
    __syncthreads();
    for (int d = 128; d > 0; d >>= 1) {
        if (t < d) sh[t] += sh[t + d];
        __syncthreads();
    }
    if (t == 0) bsum[blockIdx.x] = sh[0];
}

__global__ void bscan_kernel(const int* __restrict__ bsum, int* __restrict__ bbase, int nb) {
    int t = threadIdx.x;   // 256
    __shared__ int sh[256];
    sh[t] = (t < nb) ? bsum[t] : 0;
    __syncthreads();
    for (int d = 1; d < 256; d <<= 1) {
        int v = (t >= d) ? sh[t - d] : 0;
        __syncthreads();
        sh[t] += v;
        __syncthreads();
    }
    if (t < nb) bbase[t] = (t == 0) ? 0 : sh[t - 1];
}

__global__ void offs_kernel(const int* __restrict__ hist, const int* __restrict__ bbase,
                            int* __restrict__ offs, int* __restrict__ cursor) {
    int t = threadIdx.x;
    int idx = blockIdx.x * 256 + t;
    int v = (idx < N_NODES) ? hist[idx] : 0;
    __shared__ int sh[256];
    sh[t] = v;
    __syncthreads();
    for (int d = 1; d < 256; d <<= 1) {
        int u = (t >= d) ? sh[t - d] : 0;
        __syncthreads();
        sh[t] += u;
        __syncthreads();
    }
    if (idx < N_NODES) {
        int o = bbase[blockIdx.x] + sh[t] - v;   // exclusive
        offs[idx] = o;
        cursor[idx] = o;
    }
    if (idx == 0) offs[N_NODES] = N_EDGES;
}

__global__ void gexc_kernel(const int* __restrict__ in, const int* __restrict__ bbase,
                            int* __restrict__ out, int n) {
    int t = threadIdx.x;
    int idx = blockIdx.x * 256 + t;
    int v = (idx < n) ? in[idx] : 0;
    __shared__ int sh[256];
    sh[t] = v;
    __syncthreads();
    for (int d = 1; d < 256; d <<= 1) {
        int u = (t >= d) ? sh[t - d] : 0;
        __syncthreads();
        sh[t] += u;
        __syncthreads();
    }
    if (idx < n) out[idx] = bbase[blockIdx.x] + sh[t] - v;
}

__global__ void fill_kernel(const int* __restrict__ src, const int* __restrict__ dst,
                            int* __restrict__ cursor, int* __restrict__ esrc) {
    int e = blockIdx.x * 256 + threadIdx.x;
    if (e < N_EDGES) {
        int d = dst[e];
        int pos = atomicAdd(&cursor[d], 1);
        esrc[pos] = src[e];
    }
}

// ---------------- degree sort (block-local LDS counting sort) ----------------
__global__ void dhist_kernel(const int* __restrict__ offs, int* __restrict__ dhB) {
    __shared__ int h[256];
    int t = threadIdx.x;
    h[t] = 0;
    __syncthreads();
    int n = blockIdx.x * 256 + t;
    if (n < N_NODES) {
        int deg = offs[n + 1] - offs[n];
        if (deg > 255) deg = 255;
        atomicAdd(&h[deg], 1);               // LDS atomic, block-local
    }
    __syncthreads();
    dhB[t * SCAN_BLOCKS + blockIdx.x] = h[t];
}

__global__ void dfill_kernel(const int* __restrict__ offs, const int* __restrict__ dsB,
                             int* __restrict__ perm) {
    __shared__ int base[256];
    int t = threadIdx.x;
    base[t] = dsB[t * SCAN_BLOCKS + blockIdx.x];
    __syncthreads();
    int n = blockIdx.x * 256 + t;
    if (n < N_NODES) {
        int deg = offs[n + 1] - offs[n];
        if (deg > 255) deg = 255;
        int pos = atomicAdd(&base[deg], 1);  // LDS atomic
        perm[pos] = n;
    }
}

// ---------------- layer1 MFMA GEMM -> channel-group-major outputs ----------------
__global__ __launch_bounds__(256) void gemm1_kernel(const unsigned short* __restrict__ Ab,
                                                    const unsigned short* __restrict__ Bp,
                                                    const float* __restrict__ bias,
                                                    unsigned short* __restrict__ Kout,
                                                    unsigned short* __restrict__ Sout,
                                                    unsigned short* __restrict__ QVout,
                                                    int M) {
    __shared__ __align__(16) unsigned char As[32768];
    const int tid = threadIdx.x;
    const int w = tid >> 6, l = tid & 63;
    const int lx = l & 15, lg = l >> 4;
    const int row0 = blockIdx.x * 128;
    const bool isKS = (blockIdx.y == 0);

#pragma unroll
    for (int i = 0; i < 8; ++i) {
        int id = i * 256 + tid;
        int r = id >> 4, c = id & 15;
        int gr = row0 + r;
        short8v v;
#pragma unroll
        for (int j = 0; j < 8; ++j) v[j] = 0;
        if (gr < M) v = *(const short8v*)(Ab + (size_t)gr * 128 + c * 8);
        *(short8v*)(As + r * 256 + ((c ^ (r & 7)) << 4)) = v;
    }
    __syncthreads();

    float4v acc[2][16];
#pragma unroll
    for (int m = 0; m < 2; ++m)
#pragma unroll
        for (int n = 0; n < 16; ++n)
#pragma unroll
            for (int q = 0; q < 4; ++q) acc[m][n][q] = 0.f;

    const int ctA = isKS ? 0 : 8;
    const int ctB = isKS ? 24 : 16;
#pragma unroll
    for (int ks = 0; ks < 4; ++ks) {
        short8v a[2];
#pragma unroll
        for (int m = 0; m < 2; ++m) {
            int rl = 32 * w + 16 * m + lx;
            int cc = ks * 4 + lg;
            a[m] = *(const short8v*)(As + rl * 256 + ((cc ^ (rl & 7)) << 4));
        }
#pragma unroll
        for (int n = 0; n < 16; ++n) {
            int ct = (n < 8) ? (ctA + n) : (ctB + n - 8);
            short8v b = *(const short8v*)(Bp + (size_t)((ct * 4 + ks) * 64 + l) * 8);
            acc[0][n] = __builtin_amdgcn_mfma_f32_16x16x32_bf16(a[0], b, acc[0][n], 0, 0, 0);
            acc[1][n] = __builtin_amdgcn_mfma_f32_16x16x32_bf16(a[1], b, acc[1][n], 0, 0, 0);
        }
    }

    const int colA0 = isKS ? 0 : 128;
    const int colB0 = isKS ? 384 : 256;
    float bbA[8], bbB[8];
#pragma unroll
    for (int n = 0; n < 8; ++n) {
        bbA[n] = bias[colA0 + 16 * n + lx];
        bbB[n] = bias[colB0 + 16 * n + lx];
    }

    const int rl0 = 32 * w + 4 * lg;
    unsigned short* lds16 = (unsigned short*)As;

    if (isKS) {
        for (int plane = 0; plane < 2; ++plane) {
            __syncthreads();
#pragma unroll
            for (int m = 0; m < 2; ++m)
#pragma unroll
                for (int reg = 0; reg < 4; ++reg) {
                    int r = rl0 + 16 * m + reg;
#pragma unroll
                    for (int n = 0; n < 8; ++n) {
                        float val = acc[m][plane * 8 + n][reg] + (plane ? bbB[n] : bbA[n]);
                        if (plane == 0) val = -NLOG2E * val;
                        int eff = (lx >> 3) ^ ((r >> 2) & 1);
                        lds16[(n * 4096 + r * 32 + (eff << 4) + (lx & 7) * 2) >> 1] = f2bf(val);
                    }
                }
            __syncthreads();
            unsigned short* Out = plane ? Sout : Kout;
#pragma unroll
            for (int i = 0; i < 8; ++i) {
                int id = i * 256 + tid;
                int g = id >> 8, rem = id & 255;
                int r = rem >> 1, half = rem & 1;
                int eff = half ^ ((r >> 2) & 1);
                int gr = row0 + r;
                if (gr < M) {
                    short8v v = *(const short8v*)(As + g * 4096 + r * 32 + (eff << 4));
                    *(short8v*)(Out + (size_t)g * 800000 + gr * 16 + half * 8) = v;
                }
            }
        }
    } else {
        for (int h = 0; h < 2; ++h) {
            __syncthreads();
#pragma unroll
            for (int m = 0; m < 2; ++m)
#pragma unroll
                for (int reg = 0; reg < 4; ++reg) {
                    int r = rl0 + 16 * m + reg;
                    if ((r >> 6) == h) {
                        int rr = r & 63;
#pragma unroll
                        for (int n = 0; n < 8; ++n) {
                            float qval = -NLOG2E * (acc[m][n][reg] + bbA[n]);
                            float vval = acc[m][8 + n][reg] + bbB[n];
                            int eff = (lx >> 2) ^ ((rr >> 2) & 3);
                            int off = n * 4096 + rr * 64 + (eff << 4) + (lx & 3) * 4;
                            lds16[off >> 1]       = f2bf(qval);
                            lds16[(off >> 1) + 1] = f2bf(vval);
                        }
                    }
                }
            __syncthreads();
#pragma unroll
            for (int i = 0; i < 8; ++i) {
                int id = i * 256 + tid;
                int g = id >> 8, rem = id & 255;
                int rr = rem >> 2, ch = rem & 3;
                int eff = ch ^ ((rr >> 2) & 3);
                int gr = row0 + h * 64 + rr;
                if (gr < M) {
                    short8v v = *(const short8v*)(As + g * 4096 + rr * 64 + (eff << 4));
                    *(short8v*)(QVout + (size_t)g * 1600000 + gr * 32 + ch * 8) = v;
                }
            }
        }
    }
}

// ---------------- layer2 MFMA GEMM -> channel-group-major outputs ----------------
__global__ __launch_bounds__(256) void gemm2_kernel(const unsigned short* __restrict__ H1g,
                                                    const unsigned short* __restrict__ Bp,
                                                    const float* __restrict__ bias,
                                                    unsigned short* __restrict__ Kout,
                                                    unsigned short* __restrict__ Sout,
                                                    unsigned short* __restrict__ QVout,
                                                    int M) {
    __shared__ __align__(16) unsigned char As[32768];
    const int tid = threadIdx.x;
    const int w = tid >> 6, l = tid & 63;
    const int lx = l & 15, lg = l >> 4;
    const int row0 = blockIdx.x * 128;
    unsigned short* lds16 = (unsigned short*)As;

#pragma unroll
    for (int i = 0; i < 8; ++i) {
        int id = i * 256 + tid;
        int g = id >> 8, rem = id & 255;
        int r = rem >> 1, half = rem & 1;
        int gr = row0 + r;
        short8v v;
#pragma unroll
        for (int j = 0; j < 8; ++j) v[j] = 0;
        if (gr < M) v = *(const short8v*)(H1g + (size_t)g * 800000 + gr * 16 + half * 8);
        int cc = 2 * g + half;
        *(short8v*)(As + r * 256 + ((cc ^ (r & 7)) << 4)) = v;
    }
    __syncthreads();

    float4v acc[2][16];
#pragma unroll
    for (int m = 0; m < 2; ++m)
#pragma unroll
        for (int n = 0; n < 16; ++n)
#pragma unroll
            for (int q = 0; q < 4; ++q) acc[m][n][q] = 0.f;

#pragma unroll
    for (int ks = 0; ks < 4; ++ks) {
        short8v a[2];
#pragma unroll
        for (int m = 0; m < 2; ++m) {
            int rl = 32 * w + 16 * m + lx;
            int cc = ks * 4 + lg;
            a[m] = *(const short8v*)(As + rl * 256 + ((cc ^ (rl & 7)) << 4));
        }
#pragma unroll
        for (int n = 0; n < 16; ++n) {
            short8v b = *(const short8v*)(Bp + (size_t)((n * 4 + ks) * 64 + l) * 8);
            acc[0][n] = __builtin_amdgcn_mfma_f32_16x16x32_bf16(a[0], b, acc[0][n], 0, 0, 0);
            acc[1][n] = __builtin_amdgcn_mfma_f32_16x16x32_bf16(a[1], b, acc[1][n], 0, 0, 0);
        }
    }

    float bbk[4], bbq[4], bbv[4], bbs[4];
#pragma unroll
    for (int n = 0; n < 4; ++n) {
        bbk[n] = bias[16 * n + lx];
        bbq[n] = bias[64 + 16 * n + lx];
        bbv[n] = bias[128 + 16 * n + lx];
        bbs[n] = bias[192 + 16 * n + lx];
    }

    const int rl0 = 32 * w + 4 * lg;
    __syncthreads();
#pragma unroll
    for (int m = 0; m < 2; ++m)
#pragma unroll
        for (int reg = 0; reg < 4; ++reg) {
            int r = rl0 + 16 * m + reg;
#pragma unroll
            for (int n = 0; n < 4; ++n) {
                int c = 16 * n + lx;
                int g = c >> 3, cc = c & 7;
                int off = g * 2048 + r * 16 + cc * 2;
                lds16[off >> 1]           = f2bf(-NLOG2E * (acc[m][n][reg] + bbk[n]));
                lds16[(16384 + off) >> 1] = f2bf(acc[m][12 + n][reg] + bbs[n]);
            }
        }
    __syncthreads();
#pragma unroll
    for (int i = 0; i < 8; ++i) {
        int id = i * 256 + tid;
        int half = id >> 10, id2 = id & 1023;
        int g = id2 >> 7, r = id2 & 127;
        int gr = row0 + r;
        if (gr < M) {
            short8v v = *(const short8v*)(As + half * 16384 + g * 2048 + r * 16);
            unsigned short* Out = half ? Sout : Kout;
            *(short8v*)(Out + (size_t)g * 400000 + gr * 8) = v;
        }
    }
    __syncthreads();
#pragma unroll
    for (int m = 0; m < 2; ++m)
#pragma unroll
        for (int reg = 0; reg < 4; ++reg) {
            int r = rl0 + 16 * m + reg;
#pragma unroll
            for (int n = 0; n < 4; ++n) {
                int c = 16 * n + lx;
                int g = c >> 3, cc = c & 7;
                int eff = (cc >> 2) ^ ((r >> 2) & 1);
                int off = g * 4096 + r * 32 + (eff << 4) + (cc & 3) * 4;
                lds16[off >> 1]       = f2bf(-NLOG2E * (acc[m][4 + n][reg] + bbq[n]));
                lds16[(off >> 1) + 1] = f2bf(acc[m][8 + n][reg] + bbv[n]);
            }
        }
    __syncthreads();
#pragma unroll
    for (int i = 0; i < 8; ++i) {
        int id = i * 256 + tid;
        int g = id >> 8, rem = id & 255;
        int r = rem >> 1, ch = rem & 1;
        int eff = ch ^ ((r >> 2) & 1);
        int gr = row0 + r;
        if (gr < M) {
            short8v v = *(const short8v*)(As + g * 4096 + r * 32 + (eff << 4));
            *(short8v*)(QVout + (size_t)g * 800000 + gr * 16 + ch * 8) = v;
        }
    }
}

// ---------------- edge1: XCC-pinned group queues; 16 nodes/wave, lane owns 4 ch ----------------
__global__ __launch_bounds__(256) void edge1_kernel(const unsigned short* __restrict__ Kg,
                                                    const unsigned short* __restrict__ Sg,
                                                    const unsigned int* __restrict__ QVg,
                                                    const int* __restrict__ offs,
                                                    const int* __restrict__ esrc,
                                                    const int* __restrict__ perm,
                                                    int* __restrict__ qcur,
                                                    unsigned short* __restrict__ H1g) {
    __shared__ int chunk_sh;
    const int tid = threadIdx.x;
    const int w = tid >> 6;
    const int lane = tid & 63;
    const int ln = lane >> 2, lc = lane & 3;            // node slot, channel quad
    const int myxcd = xcc_id();
    for (int pass = 0; pass < 8; ++pass) {
        const int cg = (myxcd + pass) & 7;              // own group first, then steal
        const unsigned int* Q = QVg + (size_t)cg * 800000;
        const unsigned short* Kb = Kg + (size_t)cg * 800000;
        const unsigned short* Sb = Sg + (size_t)cg * 800000;
        unsigned short* Hb = H1g + (size_t)cg * 800000;
        for (;;) {
            __syncthreads();
            if (tid == 0) chunk_sh = atomicAdd(&qcur[cg], 1);
            __syncthreads();
            unsigned int chunk = (unsigned int)chunk_sh;
            if (chunk >= NCH1) break;                   // unsigned: also guards garbage
            int pidx = (int)chunk * 64 + w * 16 + ln;
            bool valid = pidx < N_NODES;
            int node = valid ? perm[pidx] : 0;
            int e0 = offs[node];
            int deg = valid ? (offs[node + 1] - e0) : 0;
            uint2 kk = *(const uint2*)(Kb + node * 16 + lc * 4);
            float k0 = u2f(kk.x << 16), k1 = u2f(kk.x & 0xffff0000u);
            float k2 = u2f(kk.y << 16), k3 = u2f(kk.y & 0xffff0000u);
            float a[4] = {0.f, 0.f, 0.f, 0.f};
            for (int t = 0; __any(t < deg); ++t) {
                if (t < deg) {
                    int s = esrc[e0 + t];
                    uint4 g = *(const uint4*)(Q + (size_t)s * 16 + lc * 4);
                    gacc4(g, k0, k1, k2, k3, a);
                }
            }
            if (valid) {
                uint2 ss = *(const uint2*)(Sb + node * 16 + lc * 4);
                float s0 = u2f(ss.x << 16), s1 = u2f(ss.x & 0xffff0000u);
                float s2 = u2f(ss.y << 16), s3 = u2f(ss.y & 0xffff0000u);
                ushort4 o;
                o.x = f2bf(fmaxf(s0 + a[0], 0.f));
                o.y = f2bf(fmaxf(s1 + a[1], 0.f));
                o.z = f2bf(fmaxf(s2 + a[2], 0.f));
                o.w = f2bf(fmaxf(s3 + a[3], 0.f));
                *(ushort4*)(Hb + node * 16 + lc * 4) = o;
            }
        }
    }
}

// ---------------- edge2: XCC-pinned group queues; 32 nodes/wave, lane owns 4 ch ----------------
__global__ __launch_bounds__(256) void edge2_kernel(const unsigned short* __restrict__ Kg,
                                                    const unsigned short* __restrict__ Sg,
                                                    const unsigned int* __restrict__ QVg,
                                                    const int* __restrict__ offs,
                                                    const int* __restrict__ esrc,
                                                    const int* __restrict__ perm,
                                                    int* __restrict__ qcur,
                                                    float* __restrict__ H2g) {
    __shared__ int chunk_sh;
    const int tid = threadIdx.x;
    const int w = tid >> 6;
    const int lane = tid & 63;
    const int ln = lane >> 1, lc = lane & 1;            // node slot, channel quad (of 8 ch)
    const int myxcd = xcc_id();
    for (int pass = 0; pass < 8; ++pass) {
        const int cg = (myxcd + pass) & 7;
        const unsigned int* Q = QVg + (size_t)cg * 400000;
        const unsigned short* Kb = Kg + (size_t)cg * 400000;
        const unsigned short* Sb = Sg + (size_t)cg * 400000;
        float* Hb = H2g + (size_t)cg * 400000;
        for (;;) {
            __syncthreads();
            if (tid == 0) chunk_sh = atomicAdd(&qcur[cg], 1);
            __syncthreads();
            unsigned int chunk = (unsigned int)chunk_sh;
            if (chunk >= NCH2) break;
            int pidx = (int)chunk * 128 + w * 32 + ln;
            bool valid = pidx < N_NODES;
            int node = valid ? perm[pidx] : 0;
            int e0 = offs[node];
            int deg = valid ? (offs[node + 1] - e0) : 0;
            uint2 kk = *(const uint2*)(Kb + node * 8 + lc * 4);
            float k0 = u2f(kk.x << 16), k1 = u2f(kk.x & 0xffff0000u);
            float k2 = u2f(kk.y << 16), k3 = u2f(kk.y & 0xffff0000u);
            float a[4] = {0.f, 0.f, 0.f, 0.f};
            for (int t = 0; __any(t < deg); ++t) {
                if (t < deg) {
                    int s = esrc[e0 + t];
                    uint4 g = *(const uint4*)(Q + (size_t)s * 8 + lc * 4);
                    gacc4(g, k0, k1, k2, k3, a);
                }
            }
            if (valid) {
                uint2 ss = *(const uint2*)(Sb + node * 8 + lc * 4);
                float s0 = u2f(ss.x << 16), s1 = u2f(ss.x & 0xffff0000u);
                float s2 = u2f(ss.y << 16), s3 = u2f(ss.y & 0xffff0000u);
                float4 o;
                o.x = fmaxf(s0 + a[0], 0.f);
                o.y = fmaxf(s1 + a[1], 0.f);
                o.z = fmaxf(s2 + a[2], 0.f);
                o.w = fmaxf(s3 + a[3], 0.f);
                *(float4*)(Hb + node * 8 + lc * 4) = o;
            }
        }
    }
}

// ---------------- pooling ----------------
__global__ void bounds_kernel(const int* __restrict__ batch, int* __restrict__ sg,
                              int* __restrict__ eg) {
    int n = blockIdx.x * 256 + threadIdx.x;
    if (n >= N_NODES) return;
    int b = batch[n];
    if (n == 0) {
        sg[b] = 0;
    } else {
        int p = batch[n - 1];
        if (p != b) { sg[b] = n; eg[p] = n - 1; }
    }
    if (n == N_NODES - 1) eg[b] = N_NODES - 1;
}

__global__ void pool_kernel(const float* __restrict__ H2g, const int* __restrict__ sg,
                            const int* __restrict__ eg, float* __restrict__ pooled) {
    int g = blockIdx.x;
    int s = sg[g], e = eg[g];
    int ch = threadIdx.x & 63, sub = threadIdx.x >> 6;
    int grp = ch >> 3, within = ch & 7;
    const float* base = H2g + (size_t)grp * 400000 + within;
    float acc = 0.f;
    for (int n = s + sub; n <= e; n += 4) acc += base[(size_t)n * 8];
    __shared__ float red[4][64];
    red[sub][ch] = acc;
    __syncthreads();
    if (sub == 0) {
        float v = red[0][ch] + red[1][ch] + red[2][ch] + red[3][ch];
        int cnt = e - s + 1;
        if (cnt < 1) cnt = 1;
        pooled[g * 64 + ch] = v / (float)cnt;
    }
}

__global__ void fc_kernel(const float* __restrict__ pooled, const float* __restrict__ wfc,
                          const float* __restrict__ bfc, float* __restrict__ out) {
    int t = threadIdx.x;          // 128
    int g = t >> 1, c = t & 1;
    float s = bfc[c];
#pragma unroll
    for (int i = 0; i < 64; ++i) s += pooled[g * 64 + i] * wfc[c * 64 + i];
    out[g * 2 + c] = s;
}

// ---------------- launch ----------------
extern "C" void kernel_launch(void* const* d_in, const int* in_sizes, int n_in,
                              void* d_out, int out_size, void* d_ws, size_t ws_size,
                              hipStream_t stream) {
    (void)in_sizes; (void)n_in; (void)out_size; (void)ws_size;
    const float* x    = (const float*)d_in[0];
    const int*   ei   = (const int*)d_in[1];
    const int*   batch= (const int*)d_in[2];
    const float* w1k = (const float*)d_in[3];  const float* b1k = (const float*)d_in[4];
    const float* w1q = (const float*)d_in[5];  const float* b1q = (const float*)d_in[6];
    const float* w1v = (const float*)d_in[7];  const float* b1v = (const float*)d_in[8];
    const float* w1s = (const float*)d_in[9];  const float* b1s = (const float*)d_in[10];
    const float* w2k = (const float*)d_in[11]; const float* b2k = (const float*)d_in[12];
    const float* w2q = (const float*)d_in[13]; const float* b2q = (const float*)d_in[14];
    const float* w2v = (const float*)d_in[15]; const float* b2v = (const float*)d_in[16];
    const float* w2s = (const float*)d_in[17]; const float* b2s = (const float*)d_in[18];
    const float* wfc = (const float*)d_in[19]; const float* bfc = (const float*)d_in[20];
    float* out = (float*)d_out;

    char* ws = (char*)d_ws;
    unsigned short* K1  = (unsigned short*)(ws + OFF_K1);
    unsigned short* S1  = (unsigned short*)(ws + OFF_S1);
    unsigned short* QV1 = (unsigned short*)(ws + OFF_QV1);
    unsigned short* H1B = (unsigned short*)(ws + OFF_H1B);
    unsigned short* XB  = (unsigned short*)(ws + OFF_XB);
    unsigned short* K2  = (unsigned short*)(ws + OFF_K2);
    unsigned short* S2  = (unsigned short*)(ws + OFF_S2);
    unsigned short* QV2 = (unsigned short*)(ws + OFF_QV2);
    float* H2   = (float*)(ws + OFF_H2);
    int*   esrc = (int*)(ws + OFF_ESRC);
    int*   offs = (int*)(ws + OFF_OFFS);
    int*   curs = (int*)(ws + OFF_CURS);
    int*   bsum = (int*)(ws + OFF_BSUM);
    int*   bbas = (int*)(ws + OFF_BBAS);
    unsigned short* BP1 = (unsigned short*)(ws + OFF_BP1);
    float* bc1  = (float*)(ws + OFF_BC1);
    unsigned short* BP2 = (unsigned short*)(ws + OFF_BP2);
    float* bc2  = (float*)(ws + OFF_BC2);
    int*   sg   = (int*)(ws + OFF_SG);
    int*   eg   = (int*)(ws + OFF_EG);
    float* pl   = (float*)(ws + OFF_PL);
    int*   perm = (int*)(ws + OFF_PERM);
    int*   dhB  = (int*)(ws + OFF_DHB);
    int*   dsB  = (int*)(ws + OFF_DSB);
    int*   db2  = (int*)(ws + OFF_DB2);
    int*   db3  = (int*)(ws + OFF_DB3);
    int*   qc1  = (int*)(ws + OFF_QC1);
    int*   qc2  = (int*)(ws + OFF_QC2);

    const int* src = ei;
    const int* dst = ei + N_EDGES;

    // prep
    prep1_kernel<<<32, 256, 0, stream>>>(w1k, b1k, w1q, b1q, w1v, b1v, w1s, b1s, BP1, bc1);
    prep2_kernel<<<16, 256, 0, stream>>>(w2k, b2k, w2q, b2q, w2v, b2v, w2s, b2s, BP2, bc2);
    cast_kernel<<<3125, 256, 0, stream>>>(x, XB);

    // CSR build (by dst), hierarchical scan
    hipMemsetAsync(curs, 0, N_NODES * sizeof(int), stream);
    hipMemsetAsync(qc1, 0, 64, stream);   // clears qc1 (32B) AND qc2 (32B), truly adjacent now
    hist_kernel<<<(N_EDGES + 255) / 256, 256, 0, stream>>>(dst, curs);
    bsum_kernel<<<SCAN_BLOCKS, 256, 0, stream>>>(curs, bsum, N_NODES);
    bscan_kernel<<<1, 256, 0, stream>>>(bsum, bbas, SCAN_BLOCKS);
    offs_kernel<<<SCAN_BLOCKS, 256, 0, stream>>>(curs, bbas, offs, curs);
    fill_kernel<<<(N_EDGES + 255) / 256, 256, 0, stream>>>(src, dst, curs, esrc);

    // degree sort: block-local LDS counting sort, no global atomics
    dhist_kernel<<<SCAN_BLOCKS, 256, 0, stream>>>(offs, dhB);
    bsum_kernel<<<SCAN_BLOCKS, 256, 0, stream>>>(dhB, db2, DHB_N);
    bscan_kernel<<<1, 256, 0, stream>>>(db2, db3, SCAN_BLOCKS);
    gexc_kernel<<<SCAN_BLOCKS, 256, 0, stream>>>(dhB, db3, dsB, DHB_N);
    dfill_kernel<<<SCAN_BLOCKS, 256, 0, stream>>>(offs, dsB, perm);

    // layer 1
    gemm1_kernel<<<dim3(391, 2), 256, 0, stream>>>(XB, BP1, bc1, K1, S1, QV1, N_NODES);
    edge1_kernel<<<2048, 256, 0, stream>>>(K1, S1, (const unsigned int*)QV1, offs, esrc, perm, qc1, H1B);

    // layer 2
    gemm2_kernel<<<391, 256, 0, stream>>>(H1B, BP2, bc2, K2, S2, QV2, N_NODES);
    edge2_kernel<<<2048, 256, 0, stream>>>(K2, S2, (const unsigned int*)QV2, offs, esrc, perm, qc2, H2);

    // pooling + fc
    hipMemsetAsync(sg, 0x7f, N_GRAPHS * sizeof(int), stream);
    hipMemsetAsync(eg, 0x80, N_GRAPHS * sizeof(int), stream);
    bounds_kernel<<<(N_NODES + 255) / 256, 256, 0, stream>>>(batch, sg, eg);
    pool_kernel<<<N_GRAPHS, 256, 0, stream>>>(H2, sg, eg, pl);
    fc_kernel<<<1, 128, 0, stream>>>(pl, wfc, bfc, out);
}

// Round 13
// 338.124 us; speedup vs baseline: 2.4424x; 2.4424x over previous
//
#include <hip/hip_runtime.h>
#include <hip/hip_bf16.h>
#include <math.h>

#define N_NODES 50000
#define N_EDGES 800000
#define N_GRAPHS 64
#define SCAN_BLOCKS 196   // ceil(50000/256)

typedef __attribute__((ext_vector_type(8))) short short8v;   // 8 bf16 (4 VGPRs)
typedef __attribute__((ext_vector_type(4))) float float4v;   // MFMA acc

// ---------------- workspace layout (bytes) ----------------
static constexpr size_t OFF_K1   = 0;            // bf16 [50000][128] (pre-scaled -log2e) 12.8MB
static constexpr size_t OFF_S1   = 12800000;     // bf16 [50000][128]
static constexpr size_t OFF_QV1  = 25600000;     // bf16 [50000][256] interleaved q',v  25.6MB
static constexpr size_t OFF_H1B  = 51200000;     // bf16 [50000][128]
static constexpr size_t OFF_XB   = 64000000;     // bf16 [50000][128]
// layer2 overlays layer1 buffers (K1/S1/QV1 dead after edge1):
static constexpr size_t OFF_K2   = 0;            // bf16 [50000][64] (pre-scaled)
static constexpr size_t OFF_S2   = 6400000;      // bf16 [50000][64]
static constexpr size_t OFF_QV2  = 12800000;     // bf16 [50000][128] interleaved
static constexpr size_t OFF_H2   = 25600000;     // f32 [50000][64]
static constexpr size_t OFF_ESRC = 76800000;     // 3.2 MB
static constexpr size_t OFF_OFFS = 80000000;     // 50001*4 -> pad
static constexpr size_t OFF_CURS = 80200064;     // 50000*4 (hist, then cursor)
static constexpr size_t OFF_BSUM = 80400064;     // 196*4
static constexpr size_t OFF_BBAS = 80400848;
static constexpr size_t OFF_BP1  = 80401664;     // bf16 packed 128*512
static constexpr size_t OFF_BC1  = 80532736;     // 512*4
static constexpr size_t OFF_BP2  = 80534784;     // bf16 packed 128*256
static constexpr size_t OFF_BC2  = 80600320;     // 256*4
static constexpr size_t OFF_SG   = 80601344;
static constexpr size_t OFF_EG   = 80601600;
static constexpr size_t OFF_PL   = 80601856;     // 64*64*4

#define NLOG2E 1.44269504f   // gate = rcp(1 + exp2(k' + q')), k'/q' pre-scaled by -log2e

__device__ inline unsigned short f2bf(float f) {
    __hip_bfloat16 h = __float2bfloat16(f);
    union { __hip_bfloat16 h; unsigned short u; } cv;
    cv.h = h;
    return cv.u;
}
__device__ inline float fast_exp2(float x) { float r; asm("v_exp_f32 %0, %1" : "=v"(r) : "v"(x)); return r; }
__device__ inline float fast_rcp (float x) { float r; asm("v_rcp_f32 %0, %1" : "=v"(r) : "v"(x)); return r; }
__device__ inline float u2f(unsigned int u) { union { unsigned int i; float f; } w; w.i = u; return w.f; }

// accumulate one edge's channel pair: qv = [q' lo | v hi]
__device__ inline void gacc2(uint2 qv, float kx, float ky, float& ax, float& ay) {
    float q0 = u2f(qv.x << 16), v0 = u2f(qv.x & 0xffff0000u);
    float q1 = u2f(qv.y << 16), v1 = u2f(qv.y & 0xffff0000u);
    ax += v0 * fast_rcp(1.f + fast_exp2(kx + q0));
    ay += v1 * fast_rcp(1.f + fast_exp2(ky + q1));
}
__device__ inline void gacc1(unsigned int qv, float k, float& a) {
    float q = u2f(qv << 16), v = u2f(qv & 0xffff0000u);
    a += v * fast_rcp(1.f + fast_exp2(k + q));
}

// ---------------- x -> bf16 cast ----------------
__global__ void cast_kernel(const float* __restrict__ x, unsigned short* __restrict__ xb) {
    int id = blockIdx.x * 256 + threadIdx.x;
    float4 v0 = *(const float4*)&x[(size_t)id * 8];
    float4 v1 = *(const float4*)&x[(size_t)id * 8 + 4];
    short8v o;
    o[0] = (short)f2bf(v0.x); o[1] = (short)f2bf(v0.y);
    o[2] = (short)f2bf(v0.z); o[3] = (short)f2bf(v0.w);
    o[4] = (short)f2bf(v1.x); o[5] = (short)f2bf(v1.y);
    o[6] = (short)f2bf(v1.z); o[7] = (short)f2bf(v1.w);
    *(short8v*)(xb + (size_t)id * 8) = o;
}

// ---------------- weight prep: pack into MFMA B-fragment order ----------------
__global__ void prep1_kernel(const float* __restrict__ wk, const float* __restrict__ bk,
                             const float* __restrict__ wq, const float* __restrict__ bq,
                             const float* __restrict__ wv, const float* __restrict__ bv,
                             const float* __restrict__ ws, const float* __restrict__ bs,
                             unsigned short* __restrict__ Bp, float* __restrict__ bcat) {
    int id = blockIdx.x * 256 + threadIdx.x;      // 8192 total
    if (id < 8192) {
        int l = id & 63, ks = (id >> 6) & 3, ct = id >> 8;
        int c = ct * 16 + (l & 15);
        int g = c >> 7, n = c & 127;
        const float* W = (g == 0) ? wk : (g == 1) ? wq : (g == 2) ? wv : ws;
        int kb = ks * 32 + ((l >> 4) << 3);
        short8v o;
#pragma unroll
        for (int j = 0; j < 8; ++j) o[j] = (short)f2bf(W[n * 128 + kb + j]);
        *(short8v*)(Bp + (size_t)id * 8) = o;
    }
    if (id < 512) {
        int g = id >> 7, n = id & 127;
        const float* B = (g == 0) ? bk : (g == 1) ? bq : (g == 2) ? bv : bs;
        bcat[id] = B[n];
    }
}

__global__ void prep2_kernel(const float* __restrict__ wk, const float* __restrict__ bk,
                             const float* __restrict__ wq, const float* __restrict__ bq,
                             const float* __restrict__ wv, const float* __restrict__ bv,
                             const float* __restrict__ ws, const float* __restrict__ bs,
                             unsigned short* __restrict__ Bp, float* __restrict__ bcat) {
    int id = blockIdx.x * 256 + threadIdx.x;      // 4096 total
    if (id < 4096) {
        int l = id & 63, ks = (id >> 6) & 3, ct = id >> 8;
        int c = ct * 16 + (l & 15);
        int g = c >> 6, n = c & 63;
        const float* W = (g == 0) ? wk : (g == 1) ? wq : (g == 2) ? wv : ws;
        int kb = ks * 32 + ((l >> 4) << 3);
        short8v o;
#pragma unroll
        for (int j = 0; j < 8; ++j) o[j] = (short)f2bf(W[n * 128 + kb + j]);
        *(short8v*)(Bp + (size_t)id * 8) = o;
    }
    if (id < 256) {
        int g = id >> 6, n = id & 63;
        const float* B = (g == 0) ? bk : (g == 1) ? bq : (g == 2) ? bv : bs;
        bcat[id] = B[n];
    }
}

// ---------------- CSR build (plain dst buckets) ----------------
__global__ void hist_kernel(const int* __restrict__ dst, int* __restrict__ hist) {
    int e = blockIdx.x * 256 + threadIdx.x;
    if (e < N_EDGES) atomicAdd(&hist[dst[e]], 1);
}

__global__ void bsum_kernel(const int* __restrict__ hist, int* __restrict__ bsum) {
    int t = threadIdx.x;
    int idx = blockIdx.x * 256 + t;
    __shared__ int sh[256];
    sh[t] = (idx < N_NODES) ? hist[idx] : 0;
    __syncthreads();
    for (int d = 128; d > 0; d >>= 1) {
        if (t < d) sh[t] += sh[t + d];
        __syncthreads();
    }
    if (t == 0) bsum[blockIdx.x] = sh[0];
}

__global__ void bscan_kernel(const int* __restrict__ bsum, int* __restrict__ bbase) {
    int t = threadIdx.x;   // 256
    __shared__ int sh[256];
    sh[t] = (t < SCAN_BLOCKS) ? bsum[t] : 0;
    __syncthreads();
    for (int d = 1; d < 256; d <<= 1) {
        int v = (t >= d) ? sh[t - d] : 0;
        __syncthreads();
        sh[t] += v;
        __syncthreads();
    }
    if (t < SCAN_BLOCKS) bbase[t] = (t == 0) ? 0 : sh[t - 1];
}

__global__ void offs_kernel(const int* __restrict__ hist, const int* __restrict__ bbase,
                            int* __restrict__ offs, int* __restrict__ cursor) {
    int t = threadIdx.x;
    int idx = blockIdx.x * 256 + t;
    int v = (idx < N_NODES) ? hist[idx] : 0;
    __shared__ int sh[256];
    sh[t] = v;
    __syncthreads();
    for (int d = 1; d < 256; d <<= 1) {
        int u = (t >= d) ? sh[t - d] : 0;
        __syncthreads();
        sh[t] += u;
        __syncthreads();
    }
    if (idx < N_NODES) {
        int o = bbase[blockIdx.x] + sh[t] - v;   // exclusive
        offs[idx] = o;
        cursor[idx] = o;                          // cursor aliases hist: per-index RAW only
    }
    if (idx == 0) offs[N_NODES] = N_EDGES;
}

__global__ void fill_kernel(const int* __restrict__ src, const int* __restrict__ dst,
                            int* __restrict__ cursor, int* __restrict__ esrc) {
    int e = blockIdx.x * 256 + threadIdx.x;
    if (e < N_EDGES) {
        int d = dst[e];
        int pos = atomicAdd(&cursor[d], 1);
        esrc[pos] = src[e];
    }
}

// ---------------- bf16 MFMA GEMM with split epilogue (all outputs bf16) ----------------
// K and Q outputs pre-scaled by -log2e.
template <int LAYER>
__global__ __launch_bounds__(256) void gemm_mfma(const unsigned short* __restrict__ Ab,
                                                 const unsigned short* __restrict__ Bp,
                                                 const float* __restrict__ bias,
                                                 unsigned short* __restrict__ Kout,
                                                 unsigned short* __restrict__ Sout,
                                                 unsigned short* __restrict__ QVout,
                                                 int M) {
    __shared__ __align__(16) unsigned char As[32768];
    const int tid = threadIdx.x;
    const int w = tid >> 6, l = tid & 63;
    const int lx = l & 15, lg = l >> 4;
    const int row0 = blockIdx.x * 128;
    const int colb = blockIdx.y * 128;

#pragma unroll
    for (int i = 0; i < 8; ++i) {
        int id = i * 256 + tid;
        int r = id >> 4, c = id & 15;
        int gr = row0 + r;
        short8v v;
#pragma unroll
        for (int j = 0; j < 8; ++j) v[j] = 0;
        if (gr < M) v = *(const short8v*)(Ab + (size_t)gr * 128 + c * 8);
        *(short8v*)(As + r * 256 + ((c ^ (r & 7)) << 4)) = v;
    }
    __syncthreads();

    float4v acc[2][8];
#pragma unroll
    for (int m = 0; m < 2; ++m)
#pragma unroll
        for (int n = 0; n < 8; ++n)
#pragma unroll
            for (int q = 0; q < 4; ++q) acc[m][n][q] = 0.f;

    const int ct0 = blockIdx.y * 8;
#pragma unroll
    for (int ks = 0; ks < 4; ++ks) {
        short8v a[2];
#pragma unroll
        for (int m = 0; m < 2; ++m) {
            int rl = 32 * w + 16 * m + lx;
            int cc = ks * 4 + lg;
            a[m] = *(const short8v*)(As + rl * 256 + ((cc ^ (rl & 7)) << 4));
        }
#pragma unroll
        for (int n = 0; n < 8; ++n) {
            short8v b = *(const short8v*)(Bp + (size_t)(((ct0 + n) * 4 + ks) * 64 + l) * 8);
            acc[0][n] = __builtin_amdgcn_mfma_f32_16x16x32_bf16(a[0], b, acc[0][n], 0, 0, 0);
            acc[1][n] = __builtin_amdgcn_mfma_f32_16x16x32_bf16(a[1], b, acc[1][n], 0, 0, 0);
        }
    }

    float bb[8];
#pragma unroll
    for (int n = 0; n < 8; ++n) bb[n] = bias[colb + 16 * n + lx];

    const int rbase = row0 + 32 * w + 4 * lg;
#pragma unroll
    for (int m = 0; m < 2; ++m) {
#pragma unroll
        for (int reg = 0; reg < 4; ++reg) {
            int r = rbase + 16 * m + reg;
            if (r >= M) continue;
#pragma unroll
            for (int n = 0; n < 8; ++n) {
                float val = acc[m][n][reg] + bb[n];
                int c = 16 * n + lx;
                if (LAYER == 1) {
                    if (blockIdx.y == 0)      Kout[(size_t)r * 128 + c] = f2bf(-NLOG2E * val);
                    else if (blockIdx.y == 1) QVout[(size_t)r * 256 + 2 * c]     = f2bf(-NLOG2E * val);
                    else if (blockIdx.y == 2) QVout[(size_t)r * 256 + 2 * c + 1] = f2bf(val);
                    else                      Sout[(size_t)r * 128 + c] = f2bf(val);
                } else {
                    if (blockIdx.y == 0) {
                        if (c < 64) Kout[(size_t)r * 64 + c] = f2bf(-NLOG2E * val);
                        else        QVout[(size_t)r * 128 + 2 * (c - 64)] = f2bf(-NLOG2E * val);
                    } else {
                        if (c < 64) QVout[(size_t)r * 128 + 2 * c + 1] = f2bf(val);
                        else        Sout[(size_t)r * 64 + (c - 64)] = f2bf(val);
                    }
                }
            }
        }
    }
}

// ---------------- edge aggregation (gather, scalar loop, unroll-4 MLP) ----------------
__global__ __launch_bounds__(256) void edge1_kernel(const unsigned short* __restrict__ K1b,
                                                    const unsigned short* __restrict__ S1b,
                                                    const unsigned int* __restrict__ QV,
                                                    const int* __restrict__ offs,
                                                    const int* __restrict__ esrc,
                                                    unsigned short* __restrict__ H1B) {
    int node = __builtin_amdgcn_readfirstlane(blockIdx.x * 4 + (threadIdx.x >> 6));
    int lane = threadIdx.x & 63;
    unsigned int kr = *(const unsigned int*)(K1b + (size_t)node * 128 + lane * 2);
    unsigned int sr = *(const unsigned int*)(S1b + (size_t)node * 128 + lane * 2);
    float kx = u2f(kr << 16), ky = u2f(kr & 0xffff0000u);
    float sx = u2f(sr << 16), sy = u2f(sr & 0xffff0000u);
    float ax0 = 0.f, ay0 = 0.f, ax1 = 0.f, ay1 = 0.f;
    float ax2 = 0.f, ay2 = 0.f, ax3 = 0.f, ay3 = 0.f;
    int e0 = offs[node], e1 = offs[node + 1];
    int j = e0;
    for (; j + 4 <= e1; j += 4) {
        int s0 = esrc[j], s1 = esrc[j + 1], s2 = esrc[j + 2], s3 = esrc[j + 3];
        uint2 a = *(const uint2*)(QV + (size_t)s0 * 128 + lane * 2);
        uint2 b = *(const uint2*)(QV + (size_t)s1 * 128 + lane * 2);
        uint2 c = *(const uint2*)(QV + (size_t)s2 * 128 + lane * 2);
        uint2 d = *(const uint2*)(QV + (size_t)s3 * 128 + lane * 2);
        gacc2(a, kx, ky, ax0, ay0);
        gacc2(b, kx, ky, ax1, ay1);
        gacc2(c, kx, ky, ax2, ay2);
        gacc2(d, kx, ky, ax3, ay3);
    }
    for (; j < e1; ++j) {
        uint2 a = *(const uint2*)(QV + (size_t)esrc[j] * 128 + lane * 2);
        gacc2(a, kx, ky, ax0, ay0);
    }
    float rx = sx + (ax0 + ax1) + (ax2 + ax3);
    float ry = sy + (ay0 + ay1) + (ay2 + ay3);
    ushort2 o;
    o.x = f2bf(rx > 0.f ? rx : 0.f);
    o.y = f2bf(ry > 0.f ? ry : 0.f);
    *(ushort2*)(H1B + (size_t)node * 128 + lane * 2) = o;
}

__global__ __launch_bounds__(256) void edge2_kernel(const unsigned short* __restrict__ K2b,
                                                    const unsigned short* __restrict__ S2b,
                                                    const unsigned int* __restrict__ QV,
                                                    const int* __restrict__ offs,
                                                    const int* __restrict__ esrc,
                                                    float* __restrict__ H2) {
    int node = __builtin_amdgcn_readfirstlane(blockIdx.x * 4 + (threadIdx.x >> 6));
    int lane = threadIdx.x & 63;
    float k1 = u2f(((unsigned int)K2b[(size_t)node * 64 + lane]) << 16);
    float s1 = u2f(((unsigned int)S2b[(size_t)node * 64 + lane]) << 16);
    float a0 = 0.f, a1 = 0.f, a2 = 0.f, a3 = 0.f;
    int e0 = offs[node], e1 = offs[node + 1];
    int j = e0;
    for (; j + 4 <= e1; j += 4) {
        unsigned int qa = QV[(size_t)esrc[j] * 64 + lane];
        unsigned int qb = QV[(size_t)esrc[j + 1] * 64 + lane];
        unsigned int qc = QV[(size_t)esrc[j + 2] * 64 + lane];
        unsigned int qd = QV[(size_t)esrc[j + 3] * 64 + lane];
        gacc1(qa, k1, a0);
        gacc1(qb, k1, a1);
        gacc1(qc, k1, a2);
        gacc1(qd, k1, a3);
    }
    for (; j < e1; ++j) gacc1(QV[(size_t)esrc[j] * 64 + lane], k1, a0);
    float r = s1 + (a0 + a1) + (a2 + a3);
    H2[(size_t)node * 64 + lane] = r > 0.f ? r : 0.f;
}

// ---------------- pooling ----------------
__global__ void bounds_kernel(const int* __restrict__ batch, int* __restrict__ sg,
                              int* __restrict__ eg) {
    int n = blockIdx.x * 256 + threadIdx.x;
    if (n >= N_NODES) return;
    int b = batch[n];
    if (n == 0) {
        sg[b] = 0;
    } else {
        int p = batch[n - 1];
        if (p != b) { sg[b] = n; eg[p] = n - 1; }
    }
    if (n == N_NODES - 1) eg[b] = N_NODES - 1;
}

__global__ void pool_kernel(const float* __restrict__ H2, const int* __restrict__ sg,
                            const int* __restrict__ eg, float* __restrict__ pooled) {
    int g = blockIdx.x;
    int s = sg[g], e = eg[g];
    int ch = threadIdx.x & 63, sub = threadIdx.x >> 6;
    float acc = 0.f;
    for (int n = s + sub; n <= e; n += 4) acc += H2[(size_t)n * 64 + ch];
    __shared__ float red[4][64];
    red[sub][ch] = acc;
    __syncthreads();
    if (sub == 0) {
        float v = red[0][ch] + red[1][ch] + red[2][ch] + red[3][ch];
        int cnt = e - s + 1;
        if (cnt < 1) cnt = 1;
        pooled[g * 64 + ch] = v / (float)cnt;
    }
}

__global__ void fc_kernel(const float* __restrict__ pooled, const float* __restrict__ wfc,
                          const float* __restrict__ bfc, float* __restrict__ out) {
    int t = threadIdx.x;          // 128
    int g = t >> 1, c = t & 1;
    float s = bfc[c];
#pragma unroll
    for (int i = 0; i < 64; ++i) s += pooled[g * 64 + i] * wfc[c * 64 + i];
    out[g * 2 + c] = s;
}

// ---------------- launch ----------------
extern "C" void kernel_launch(void* const* d_in, const int* in_sizes, int n_in,
                              void* d_out, int out_size, void* d_ws, size_t ws_size,
                              hipStream_t stream) {
    (void)in_sizes; (void)n_in; (void)out_size; (void)ws_size;
    const float* x    = (const float*)d_in[0];
    const int*   ei   = (const int*)d_in[1];
    const int*   batch= (const int*)d_in[2];
    const float* w1k = (const float*)d_in[3];  const float* b1k = (const float*)d_in[4];
    const float* w1q = (const float*)d_in[5];  const float* b1q = (const float*)d_in[6];
    const float* w1v = (const float*)d_in[7];  const float* b1v = (const float*)d_in[8];
    const float* w1s = (const float*)d_in[9];  const float* b1s = (const float*)d_in[10];
    const float* w2k = (const float*)d_in[11]; const float* b2k = (const float*)d_in[12];
    const float* w2q = (const float*)d_in[13]; const float* b2q = (const float*)d_in[14];
    const float* w2v = (const float*)d_in[15]; const float* b2v = (const float*)d_in[16];
    const float* w2s = (const float*)d_in[17]; const float* b2s = (const float*)d_in[18];
    const float* wfc = (const float*)d_in[19]; const float* bfc = (const float*)d_in[20];
    float* out = (float*)d_out;

    char* ws = (char*)d_ws;
    unsigned short* K1  = (unsigned short*)(ws + OFF_K1);
    unsigned short* S1  = (unsigned short*)(ws + OFF_S1);
    unsigned short* QV1 = (unsigned short*)(ws + OFF_QV1);
    unsigned short* H1B = (unsigned short*)(ws + OFF_H1B);
    unsigned short* XB  = (unsigned short*)(ws + OFF_XB);
    unsigned short* K2  = (unsigned short*)(ws + OFF_K2);
    unsigned short* S2  = (unsigned short*)(ws + OFF_S2);
    unsigned short* QV2 = (unsigned short*)(ws + OFF_QV2);
    float* H2   = (float*)(ws + OFF_H2);
    int*   esrc = (int*)(ws + OFF_ESRC);
    int*   offs = (int*)(ws + OFF_OFFS);
    int*   curs = (int*)(ws + OFF_CURS);
    int*   bsum = (int*)(ws + OFF_BSUM);
    int*   bbas = (int*)(ws + OFF_BBAS);
    unsigned short* BP1 = (unsigned short*)(ws + OFF_BP1);
    float* bc1  = (float*)(ws + OFF_BC1);
    unsigned short* BP2 = (unsigned short*)(ws + OFF_BP2);
    float* bc2  = (float*)(ws + OFF_BC2);
    int*   sg   = (int*)(ws + OFF_SG);
    int*   eg   = (int*)(ws + OFF_EG);
    float* pl   = (float*)(ws + OFF_PL);

    const int* src = ei;
    const int* dst = ei + N_EDGES;

    // prep
    prep1_kernel<<<32, 256, 0, stream>>>(w1k, b1k, w1q, b1q, w1v, b1v, w1s, b1s, BP1, bc1);
    prep2_kernel<<<16, 256, 0, stream>>>(w2k, b2k, w2q, b2q, w2v, b2v, w2s, b2s, BP2, bc2);
    cast_kernel<<<3125, 256, 0, stream>>>(x, XB);

    // CSR build (by dst), hierarchical scan
    hipMemsetAsync(curs, 0, N_NODES * sizeof(int), stream);
    hist_kernel<<<(N_EDGES + 255) / 256, 256, 0, stream>>>(dst, curs);
    bsum_kernel<<<SCAN_BLOCKS, 256, 0, stream>>>(curs, bsum);
    bscan_kernel<<<1, 256, 0, stream>>>(bsum, bbas);
    offs_kernel<<<SCAN_BLOCKS, 256, 0, stream>>>(curs, bbas, offs, curs);
    fill_kernel<<<(N_EDGES + 255) / 256, 256, 0, stream>>>(src, dst, curs, esrc);

    // layer 1
    gemm_mfma<1><<<dim3(391, 4), 256, 0, stream>>>(XB, BP1, bc1, K1, S1, QV1, N_NODES);
    edge1_kernel<<<12500, 256, 0, stream>>>(K1, S1, (const unsigned int*)QV1, offs, esrc, H1B);

    // layer 2
    gemm_mfma<2><<<dim3(391, 2), 256, 0, stream>>>(H1B, BP2, bc2, K2, S2, QV2, N_NODES);
    edge2_kernel<<<12500, 256, 0, stream>>>(K2, S2, (const unsigned int*)QV2, offs, esrc, H2);

    // pooling + fc
    hipMemsetAsync(sg, 0x7f, N_GRAPHS * sizeof(int), stream);
    hipMemsetAsync(eg, 0x80, N_GRAPHS * sizeof(int), stream);
    bounds_kernel<<<(N_NODES + 255) / 256, 256, 0, stream>>>(batch, sg, eg);
    pool_kernel<<<N_GRAPHS, 256, 0, stream>>>(H2, sg, eg, pl);
    fc_kernel<<<1, 128, 0, stream>>>(pl, wfc, bfc, out);
}

// Round 14
// 326.063 us; speedup vs baseline: 2.5328x; 1.0370x over previous
//
#include <hip/hip_runtime.h>
#include <hip/hip_bf16.h>
#include <math.h>

#define N_NODES 50000
#define N_EDGES 800000
#define N_GRAPHS 64
#define SCAN_BLOCKS 196   // ceil(50000/256)

typedef __attribute__((ext_vector_type(8))) short short8v;   // 8 bf16 (4 VGPRs)
typedef __attribute__((ext_vector_type(4))) float float4v;   // MFMA acc

// ---------------- workspace layout (bytes) ----------------
static constexpr size_t OFF_K1   = 0;            // bf16 [50000][128] (pre-scaled -log2e) 12.8MB
static constexpr size_t OFF_S1   = 12800000;     // bf16 [50000][128]
static constexpr size_t OFF_QV1  = 25600000;     // bf16 [50000][256] interleaved q',v  25.6MB
static constexpr size_t OFF_H1B  = 51200000;     // bf16 [50000][128]
static constexpr size_t OFF_XB   = 64000000;     // bf16 [50000][128]
// layer2 overlays layer1 buffers (K1/S1/QV1 dead after edge1):
static constexpr size_t OFF_K2   = 0;            // bf16 [50000][64] (pre-scaled)
static constexpr size_t OFF_S2   = 6400000;      // bf16 [50000][64]
static constexpr size_t OFF_QV2  = 12800000;     // bf16 [50000][128] interleaved
static constexpr size_t OFF_H2   = 25600000;     // f32 [50000][64]
static constexpr size_t OFF_ESRC = 76800000;     // 3.2 MB
static constexpr size_t OFF_OFFS = 80000000;     // 50001*4 -> pad
static constexpr size_t OFF_CURS = 80200064;     // 50000*4 (hist, then cursor)
static constexpr size_t OFF_BSUM = 80400064;     // 196*4
static constexpr size_t OFF_BBAS = 80400848;
static constexpr size_t OFF_BP1  = 80401664;     // bf16 packed 128*512
static constexpr size_t OFF_BC1  = 80532736;     // 512*4
static constexpr size_t OFF_BP2  = 80534784;     // bf16 packed 128*256
static constexpr size_t OFF_BC2  = 80600320;     // 256*4

#define NLOG2E 1.44269504f   // gate = rcp(1 + exp2(k' + q')), k'/q' pre-scaled by -log2e

__device__ inline unsigned short f2bf(float f) {
    __hip_bfloat16 h = __float2bfloat16(f);
    union { __hip_bfloat16 h; unsigned short u; } cv;
    cv.h = h;
    return cv.u;
}
__device__ inline float fast_exp2(float x) { float r; asm("v_exp_f32 %0, %1" : "=v"(r) : "v"(x)); return r; }
__device__ inline float fast_rcp (float x) { float r; asm("v_rcp_f32 %0, %1" : "=v"(r) : "v"(x)); return r; }
__device__ inline float u2f(unsigned int u) { union { unsigned int i; float f; } w; w.i = u; return w.f; }

// accumulate one edge's channel pair: qv = [q' lo | v hi]
__device__ inline void gacc2(uint2 qv, float kx, float ky, float& ax, float& ay) {
    float q0 = u2f(qv.x << 16), v0 = u2f(qv.x & 0xffff0000u);
    float q1 = u2f(qv.y << 16), v1 = u2f(qv.y & 0xffff0000u);
    ax += v0 * fast_rcp(1.f + fast_exp2(kx + q0));
    ay += v1 * fast_rcp(1.f + fast_exp2(ky + q1));
}
__device__ inline void gacc1(unsigned int qv, float k, float& a) {
    float q = u2f(qv << 16), v = u2f(qv & 0xffff0000u);
    a += v * fast_rcp(1.f + fast_exp2(k + q));
}

// ---------------- fused prep: x cast + weight pack + bias concat ----------------
// id space: [0,800000) cast (8 elems each) | [800000,808192) BP1 | [808192,812288) BP2
//           [812288,812800) bc1 | [812800,813056) bc2
__global__ void prep_kernel(const float* __restrict__ x, unsigned short* __restrict__ xb,
                            const float* __restrict__ w1k, const float* __restrict__ b1k,
                            const float* __restrict__ w1q, const float* __restrict__ b1q,
                            const float* __restrict__ w1v, const float* __restrict__ b1v,
                            const float* __restrict__ w1s, const float* __restrict__ b1s,
                            const float* __restrict__ w2k, const float* __restrict__ b2k,
                            const float* __restrict__ w2q, const float* __restrict__ b2q,
                            const float* __restrict__ w2v, const float* __restrict__ b2v,
                            const float* __restrict__ w2s, const float* __restrict__ b2s,
                            unsigned short* __restrict__ BP1, float* __restrict__ bc1,
                            unsigned short* __restrict__ BP2, float* __restrict__ bc2) {
    int id = blockIdx.x * 256 + threadIdx.x;
    if (id < 800000) {
        float4 v0 = *(const float4*)&x[(size_t)id * 8];
        float4 v1 = *(const float4*)&x[(size_t)id * 8 + 4];
        short8v o;
        o[0] = (short)f2bf(v0.x); o[1] = (short)f2bf(v0.y);
        o[2] = (short)f2bf(v0.z); o[3] = (short)f2bf(v0.w);
        o[4] = (short)f2bf(v1.x); o[5] = (short)f2bf(v1.y);
        o[6] = (short)f2bf(v1.z); o[7] = (short)f2bf(v1.w);
        *(short8v*)(xb + (size_t)id * 8) = o;
    } else if (id < 808192) {
        int t = id - 800000;
        int l = t & 63, ks = (t >> 6) & 3, ct = t >> 8;
        int c = ct * 16 + (l & 15);
        int g = c >> 7, n = c & 127;
        const float* W = (g == 0) ? w1k : (g == 1) ? w1q : (g == 2) ? w1v : w1s;
        int kb = ks * 32 + ((l >> 4) << 3);
        short8v o;
#pragma unroll
        for (int j = 0; j < 8; ++j) o[j] = (short)f2bf(W[n * 128 + kb + j]);
        *(short8v*)(BP1 + (size_t)t * 8) = o;
    } else if (id < 812288) {
        int t = id - 808192;
        int l = t & 63, ks = (t >> 6) & 3, ct = t >> 8;
        int c = ct * 16 + (l & 15);
        int g = c >> 6, n = c & 63;
        const float* W = (g == 0) ? w2k : (g == 1) ? w2q : (g == 2) ? w2v : w2s;
        int kb = ks * 32 + ((l >> 4) << 3);
        short8v o;
#pragma unroll
        for (int j = 0; j < 8; ++j) o[j] = (short)f2bf(W[n * 128 + kb + j]);
        *(short8v*)(BP2 + (size_t)t * 8) = o;
    } else if (id < 812800) {
        int t = id - 812288;
        int g = t >> 7, n = t & 127;
        const float* B = (g == 0) ? b1k : (g == 1) ? b1q : (g == 2) ? b1v : b1s;
        bc1[t] = B[n];
    } else if (id < 813056) {
        int t = id - 812800;
        int g = t >> 6, n = t & 63;
        const float* B = (g == 0) ? b2k : (g == 1) ? b2q : (g == 2) ? b2v : b2s;
        bc2[t] = B[n];
    }
}

// ---------------- CSR build (plain dst buckets) ----------------
__global__ void hist_kernel(const int* __restrict__ dst, int* __restrict__ hist) {
    int e = blockIdx.x * 256 + threadIdx.x;
    if (e < N_EDGES) atomicAdd(&hist[dst[e]], 1);
}

__global__ void bsum_kernel(const int* __restrict__ hist, int* __restrict__ bsum) {
    int t = threadIdx.x;
    int idx = blockIdx.x * 256 + t;
    __shared__ int sh[256];
    sh[t] = (idx < N_NODES) ? hist[idx] : 0;
    __syncthreads();
    for (int d = 128; d > 0; d >>= 1) {
        if (t < d) sh[t] += sh[t + d];
        __syncthreads();
    }
    if (t == 0) bsum[blockIdx.x] = sh[0];
}

__global__ void bscan_kernel(const int* __restrict__ bsum, int* __restrict__ bbase) {
    int t = threadIdx.x;   // 256
    __shared__ int sh[256];
    sh[t] = (t < SCAN_BLOCKS) ? bsum[t] : 0;
    __syncthreads();
    for (int d = 1; d < 256; d <<= 1) {
        int v = (t >= d) ? sh[t - d] : 0;
        __syncthreads();
        sh[t] += v;
        __syncthreads();
    }
    if (t < SCAN_BLOCKS) bbase[t] = (t == 0) ? 0 : sh[t - 1];
}

__global__ void offs_kernel(const int* __restrict__ hist, const int* __restrict__ bbase,
                            int* __restrict__ offs, int* __restrict__ cursor) {
    int t = threadIdx.x;
    int idx = blockIdx.x * 256 + t;
    int v = (idx < N_NODES) ? hist[idx] : 0;
    __shared__ int sh[256];
    sh[t] = v;
    __syncthreads();
    for (int d = 1; d < 256; d <<= 1) {
        int u = (t >= d) ? sh[t - d] : 0;
        __syncthreads();
        sh[t] += u;
        __syncthreads();
    }
    if (idx < N_NODES) {
        int o = bbase[blockIdx.x] + sh[t] - v;   // exclusive
        offs[idx] = o;
        cursor[idx] = o;                          // cursor aliases hist: per-index RAW only
    }
    if (idx == 0) offs[N_NODES] = N_EDGES;
}

__global__ void fill_kernel(const int* __restrict__ src, const int* __restrict__ dst,
                            int* __restrict__ cursor, int* __restrict__ esrc) {
    int e = blockIdx.x * 256 + threadIdx.x;
    if (e < N_EDGES) {
        int d = dst[e];
        int pos = atomicAdd(&cursor[d], 1);
        esrc[pos] = src[e];
    }
}

// ---------------- bf16 MFMA GEMM with split epilogue (all outputs bf16) ----------------
// K and Q outputs pre-scaled by -log2e.
template <int LAYER>
__global__ __launch_bounds__(256) void gemm_mfma(const unsigned short* __restrict__ Ab,
                                                 const unsigned short* __restrict__ Bp,
                                                 const float* __restrict__ bias,
                                                 unsigned short* __restrict__ Kout,
                                                 unsigned short* __restrict__ Sout,
                                                 unsigned short* __restrict__ QVout,
                                                 int M) {
    __shared__ __align__(16) unsigned char As[32768];
    const int tid = threadIdx.x;
    const int w = tid >> 6, l = tid & 63;
    const int lx = l & 15, lg = l >> 4;
    const int row0 = blockIdx.x * 128;
    const int colb = blockIdx.y * 128;

#pragma unroll
    for (int i = 0; i < 8; ++i) {
        int id = i * 256 + tid;
        int r = id >> 4, c = id & 15;
        int gr = row0 + r;
        short8v v;
#pragma unroll
        for (int j = 0; j < 8; ++j) v[j] = 0;
        if (gr < M) v = *(const short8v*)(Ab + (size_t)gr * 128 + c * 8);
        *(short8v*)(As + r * 256 + ((c ^ (r & 7)) << 4)) = v;
    }
    __syncthreads();

    float4v acc[2][8];
#pragma unroll
    for (int m = 0; m < 2; ++m)
#pragma unroll
        for (int n = 0; n < 8; ++n)
#pragma unroll
            for (int q = 0; q < 4; ++q) acc[m][n][q] = 0.f;

    const int ct0 = blockIdx.y * 8;
#pragma unroll
    for (int ks = 0; ks < 4; ++ks) {
        short8v a[2];
#pragma unroll
        for (int m = 0; m < 2; ++m) {
            int rl = 32 * w + 16 * m + lx;
            int cc = ks * 4 + lg;
            a[m] = *(const short8v*)(As + rl * 256 + ((cc ^ (rl & 7)) << 4));
        }
#pragma unroll
        for (int n = 0; n < 8; ++n) {
            short8v b = *(const short8v*)(Bp + (size_t)(((ct0 + n) * 4 + ks) * 64 + l) * 8);
            acc[0][n] = __builtin_amdgcn_mfma_f32_16x16x32_bf16(a[0], b, acc[0][n], 0, 0, 0);
            acc[1][n] = __builtin_amdgcn_mfma_f32_16x16x32_bf16(a[1], b, acc[1][n], 0, 0, 0);
        }
    }

    float bb[8];
#pragma unroll
    for (int n = 0; n < 8; ++n) bb[n] = bias[colb + 16 * n + lx];

    const int rbase = row0 + 32 * w + 4 * lg;
#pragma unroll
    for (int m = 0; m < 2; ++m) {
#pragma unroll
        for (int reg = 0; reg < 4; ++reg) {
            int r = rbase + 16 * m + reg;
            if (r >= M) continue;
#pragma unroll
            for (int n = 0; n < 8; ++n) {
                float val = acc[m][n][reg] + bb[n];
                int c = 16 * n + lx;
                if (LAYER == 1) {
                    if (blockIdx.y == 0)      Kout[(size_t)r * 128 + c] = f2bf(-NLOG2E * val);
                    else if (blockIdx.y == 1) QVout[(size_t)r * 256 + 2 * c]     = f2bf(-NLOG2E * val);
                    else if (blockIdx.y == 2) QVout[(size_t)r * 256 + 2 * c + 1] = f2bf(val);
                    else                      Sout[(size_t)r * 128 + c] = f2bf(val);
                } else {
                    if (blockIdx.y == 0) {
                        if (c < 64) Kout[(size_t)r * 64 + c] = f2bf(-NLOG2E * val);
                        else        QVout[(size_t)r * 128 + 2 * (c - 64)] = f2bf(-NLOG2E * val);
                    } else {
                        if (c < 64) QVout[(size_t)r * 128 + 2 * c + 1] = f2bf(val);
                        else        Sout[(size_t)r * 64 + (c - 64)] = f2bf(val);
                    }
                }
            }
        }
    }
}

// ---------------- edge aggregation (gather, scalar loop, unroll-4 MLP) ----------------
__global__ __launch_bounds__(256) void edge1_kernel(const unsigned short* __restrict__ K1b,
                                                    const unsigned short* __restrict__ S1b,
                                                    const unsigned int* __restrict__ QV,
                                                    const int* __restrict__ offs,
                                                    const int* __restrict__ esrc,
                                                    unsigned short* __restrict__ H1B) {
    int node = __builtin_amdgcn_readfirstlane(blockIdx.x * 4 + (threadIdx.x >> 6));
    int lane = threadIdx.x & 63;
    unsigned int kr = *(const unsigned int*)(K1b + (size_t)node * 128 + lane * 2);
    unsigned int sr = *(const unsigned int*)(S1b + (size_t)node * 128 + lane * 2);
    float kx = u2f(kr << 16), ky = u2f(kr & 0xffff0000u);
    float sx = u2f(sr << 16), sy = u2f(sr & 0xffff0000u);
    float ax0 = 0.f, ay0 = 0.f, ax1 = 0.f, ay1 = 0.f;
    float ax2 = 0.f, ay2 = 0.f, ax3 = 0.f, ay3 = 0.f;
    int e0 = offs[node], e1 = offs[node + 1];
    int j = e0;
    for (; j + 4 <= e1; j += 4) {
        int s0 = esrc[j], s1 = esrc[j + 1], s2 = esrc[j + 2], s3 = esrc[j + 3];
        uint2 a = *(const uint2*)(QV + (size_t)s0 * 128 + lane * 2);
        uint2 b = *(const uint2*)(QV + (size_t)s1 * 128 + lane * 2);
        uint2 c = *(const uint2*)(QV + (size_t)s2 * 128 + lane * 2);
        uint2 d = *(const uint2*)(QV + (size_t)s3 * 128 + lane * 2);
        gacc2(a, kx, ky, ax0, ay0);
        gacc2(b, kx, ky, ax1, ay1);
        gacc2(c, kx, ky, ax2, ay2);
        gacc2(d, kx, ky, ax3, ay3);
    }
    for (; j < e1; ++j) {
        uint2 a = *(const uint2*)(QV + (size_t)esrc[j] * 128 + lane * 2);
        gacc2(a, kx, ky, ax0, ay0);
    }
    float rx = sx + (ax0 + ax1) + (ax2 + ax3);
    float ry = sy + (ay0 + ay1) + (ay2 + ay3);
    ushort2 o;
    o.x = f2bf(rx > 0.f ? rx : 0.f);
    o.y = f2bf(ry > 0.f ? ry : 0.f);
    *(ushort2*)(H1B + (size_t)node * 128 + lane * 2) = o;
}

__global__ __launch_bounds__(256) void edge2_kernel(const unsigned short* __restrict__ K2b,
                                                    const unsigned short* __restrict__ S2b,
                                                    const unsigned int* __restrict__ QV,
                                                    const int* __restrict__ offs,
                                                    const int* __restrict__ esrc,
                                                    float* __restrict__ H2) {
    int node = __builtin_amdgcn_readfirstlane(blockIdx.x * 4 + (threadIdx.x >> 6));
    int lane = threadIdx.x & 63;
    float k1 = u2f(((unsigned int)K2b[(size_t)node * 64 + lane]) << 16);
    float s1 = u2f(((unsigned int)S2b[(size_t)node * 64 + lane]) << 16);
    float a0 = 0.f, a1 = 0.f, a2 = 0.f, a3 = 0.f;
    int e0 = offs[node], e1 = offs[node + 1];
    int j = e0;
    for (; j + 4 <= e1; j += 4) {
        unsigned int qa = QV[(size_t)esrc[j] * 64 + lane];
        unsigned int qb = QV[(size_t)esrc[j + 1] * 64 + lane];
        unsigned int qc = QV[(size_t)esrc[j + 2] * 64 + lane];
        unsigned int qd = QV[(size_t)esrc[j + 3] * 64 + lane];
        gacc1(qa, k1, a0);
        gacc1(qb, k1, a1);
        gacc1(qc, k1, a2);
        gacc1(qd, k1, a3);
    }
    for (; j < e1; ++j) gacc1(QV[(size_t)esrc[j] * 64 + lane], k1, a0);
    float r = s1 + (a0 + a1) + (a2 + a3);
    H2[(size_t)node * 64 + lane] = r > 0.f ? r : 0.f;
}

// ---------------- fused pool + fc: binary-search graph bounds in sorted batch ----------------
__global__ void poolfc_kernel(const float* __restrict__ H2, const int* __restrict__ batch,
                              const float* __restrict__ wfc, const float* __restrict__ bfc,
                              float* __restrict__ out) {
    int g = blockIdx.x;
    int tid = threadIdx.x;
    __shared__ int se[2];
    if (tid == 0) {
        int lo = 0, hi = N_NODES;
        while (lo < hi) { int mid = (lo + hi) >> 1; if (batch[mid] < g) lo = mid + 1; else hi = mid; }
        se[0] = lo;
        hi = N_NODES;
        while (lo < hi) { int mid = (lo + hi) >> 1; if (batch[mid] <= g) lo = mid + 1; else hi = mid; }
        se[1] = lo;   // exclusive end
    }
    __syncthreads();
    int s = se[0], e = se[1];
    int ch = tid & 63, sub = tid >> 6;
    float acc = 0.f;
    for (int n = s + sub; n < e; n += 4) acc += H2[(size_t)n * 64 + ch];
    __shared__ float red[4][64];
    __shared__ float prow[64];
    red[sub][ch] = acc;
    __syncthreads();
    if (sub == 0) {
        float v = red[0][ch] + red[1][ch] + red[2][ch] + red[3][ch];
        int cnt = e - s;
        if (cnt < 1) cnt = 1;
        prow[ch] = v / (float)cnt;
    }
    __syncthreads();
    if (tid < 2) {
        float sacc = bfc[tid];
#pragma unroll
        for (int i = 0; i < 64; ++i) sacc += prow[i] * wfc[tid * 64 + i];
        out[g * 2 + tid] = sacc;
    }
}

// ---------------- launch ----------------
extern "C" void kernel_launch(void* const* d_in, const int* in_sizes, int n_in,
                              void* d_out, int out_size, void* d_ws, size_t ws_size,
                              hipStream_t stream) {
    (void)in_sizes; (void)n_in; (void)out_size; (void)ws_size;
    const float* x    = (const float*)d_in[0];
    const int*   ei   = (const int*)d_in[1];
    const int*   batch= (const int*)d_in[2];
    const float* w1k = (const float*)d_in[3];  const float* b1k = (const float*)d_in[4];
    const float* w1q = (const float*)d_in[5];  const float* b1q = (const float*)d_in[6];
    const float* w1v = (const float*)d_in[7];  const float* b1v = (const float*)d_in[8];
    const float* w1s = (const float*)d_in[9];  const float* b1s = (const float*)d_in[10];
    const float* w2k = (const float*)d_in[11]; const float* b2k = (const float*)d_in[12];
    const float* w2q = (const float*)d_in[13]; const float* b2q = (const float*)d_in[14];
    const float* w2v = (const float*)d_in[15]; const float* b2v = (const float*)d_in[16];
    const float* w2s = (const float*)d_in[17]; const float* b2s = (const float*)d_in[18];
    const float* wfc = (const float*)d_in[19]; const float* bfc = (const float*)d_in[20];
    float* out = (float*)d_out;

    char* ws = (char*)d_ws;
    unsigned short* K1  = (unsigned short*)(ws + OFF_K1);
    unsigned short* S1  = (unsigned short*)(ws + OFF_S1);
    unsigned short* QV1 = (unsigned short*)(ws + OFF_QV1);
    unsigned short* H1B = (unsigned short*)(ws + OFF_H1B);
    unsigned short* XB  = (unsigned short*)(ws + OFF_XB);
    unsigned short* K2  = (unsigned short*)(ws + OFF_K2);
    unsigned short* S2  = (unsigned short*)(ws + OFF_S2);
    unsigned short* QV2 = (unsigned short*)(ws + OFF_QV2);
    float* H2   = (float*)(ws + OFF_H2);
    int*   esrc = (int*)(ws + OFF_ESRC);
    int*   offs = (int*)(ws + OFF_OFFS);
    int*   curs = (int*)(ws + OFF_CURS);
    int*   bsum = (int*)(ws + OFF_BSUM);
    int*   bbas = (int*)(ws + OFF_BBAS);
    unsigned short* BP1 = (unsigned short*)(ws + OFF_BP1);
    float* bc1  = (float*)(ws + OFF_BC1);
    unsigned short* BP2 = (unsigned short*)(ws + OFF_BP2);
    float* bc2  = (float*)(ws + OFF_BC2);

    const int* src = ei;
    const int* dst = ei + N_EDGES;

    // fused prep: cast + weight pack + bias concat (813,056 ids)
    prep_kernel<<<3177, 256, 0, stream>>>(x, XB,
                                          w1k, b1k, w1q, b1q, w1v, b1v, w1s, b1s,
                                          w2k, b2k, w2q, b2q, w2v, b2v, w2s, b2s,
                                          BP1, bc1, BP2, bc2);

    // CSR build (by dst), hierarchical scan
    hipMemsetAsync(curs, 0, N_NODES * sizeof(int), stream);
    hist_kernel<<<(N_EDGES + 255) / 256, 256, 0, stream>>>(dst, curs);
    bsum_kernel<<<SCAN_BLOCKS, 256, 0, stream>>>(curs, bsum);
    bscan_kernel<<<1, 256, 0, stream>>>(bsum, bbas);
    offs_kernel<<<SCAN_BLOCKS, 256, 0, stream>>>(curs, bbas, offs, curs);
    fill_kernel<<<(N_EDGES + 255) / 256, 256, 0, stream>>>(src, dst, curs, esrc);

    // layer 1
    gemm_mfma<1><<<dim3(391, 4), 256, 0, stream>>>(XB, BP1, bc1, K1, S1, QV1, N_NODES);
    edge1_kernel<<<12500, 256, 0, stream>>>(K1, S1, (const unsigned int*)QV1, offs, esrc, H1B);

    // layer 2
    gemm_mfma<2><<<dim3(391, 2), 256, 0, stream>>>(H1B, BP2, bc2, K2, S2, QV2, N_NODES);
    edge2_kernel<<<12500, 256, 0, stream>>>(K2, S2, (const unsigned int*)QV2, offs, esrc, H2);

    // fused pooling + fc (binary search on sorted batch; no bounds kernel, no memsets)
    poolfc_kernel<<<N_GRAPHS, 256, 0, stream>>>(H2, batch, wfc, bfc, out);
}

// Round 15
// 307.967 us; speedup vs baseline: 2.6816x; 1.0588x over previous
//
#include <hip/hip_runtime.h>
#include <hip/hip_bf16.h>
#include <math.h>

#define N_NODES 50000
#define N_EDGES 800000
#define N_GRAPHS 64
#define SCAN_BLOCKS 196   // ceil(50000/256)

typedef __attribute__((ext_vector_type(8))) short short8v;   // 8 bf16 (4 VGPRs)
typedef __attribute__((ext_vector_type(4))) float float4v;   // MFMA acc

// ---------------- workspace layout (bytes) ----------------
static constexpr size_t OFF_K1   = 0;            // bf16 [50000][128] (pre-scaled -log2e) 12.8MB
static constexpr size_t OFF_S1   = 12800000;     // bf16 [50000][128]
static constexpr size_t OFF_QV1  = 25600000;     // bf16 [50000][256] interleaved q',v  25.6MB
static constexpr size_t OFF_H1B  = 51200000;     // bf16 [50000][128]
static constexpr size_t OFF_XB   = 64000000;     // bf16 [50000][128]
// layer2 overlays layer1 buffers (K1/S1/QV1 dead after edge1):
static constexpr size_t OFF_K2   = 0;            // bf16 [50000][64] (pre-scaled)
static constexpr size_t OFF_S2   = 6400000;      // bf16 [50000][64]
static constexpr size_t OFF_QV2  = 12800000;     // bf16 [50000][128] interleaved
static constexpr size_t OFF_H2   = 25600000;     // f32 [50000][64]
static constexpr size_t OFF_ESRC = 76800000;     // 3.2 MB
static constexpr size_t OFF_OFFS = 80000000;     // 50001*4 -> pad
static constexpr size_t OFF_CURS = 80200064;     // 50000*4 (hist, then cursor)
static constexpr size_t OFF_BSUM = 80400064;     // 196*4
static constexpr size_t OFF_BBAS = 80400848;
static constexpr size_t OFF_BP1  = 80401664;     // bf16 packed 128*512
static constexpr size_t OFF_BC1  = 80532736;     // 512*4
static constexpr size_t OFF_BP2  = 80534784;     // bf16 packed 128*256
static constexpr size_t OFF_BC2  = 80600320;     // 256*4
static constexpr size_t OFF_PSUM = 80601344;     // f32 [64][64] = 16384

#define NLOG2E 1.44269504f   // gate = rcp(1 + exp2(k' + q')), k'/q' pre-scaled by -log2e

__device__ inline unsigned short f2bf(float f) {
    __hip_bfloat16 h = __float2bfloat16(f);
    union { __hip_bfloat16 h; unsigned short u; } cv;
    cv.h = h;
    return cv.u;
}
__device__ inline float fast_exp2(float x) { float r; asm("v_exp_f32 %0, %1" : "=v"(r) : "v"(x)); return r; }
__device__ inline float fast_rcp (float x) { float r; asm("v_rcp_f32 %0, %1" : "=v"(r) : "v"(x)); return r; }
__device__ inline float u2f(unsigned int u) { union { unsigned int i; float f; } w; w.i = u; return w.f; }

// accumulate one edge's channel pair: qv = [q' lo | v hi]
__device__ inline void gacc2(uint2 qv, float kx, float ky, float& ax, float& ay) {
    float q0 = u2f(qv.x << 16), v0 = u2f(qv.x & 0xffff0000u);
    float q1 = u2f(qv.y << 16), v1 = u2f(qv.y & 0xffff0000u);
    ax += v0 * fast_rcp(1.f + fast_exp2(kx + q0));
    ay += v1 * fast_rcp(1.f + fast_exp2(ky + q1));
}
__device__ inline void gacc1(unsigned int qv, float k, float& a) {
    float q = u2f(qv << 16), v = u2f(qv & 0xffff0000u);
    a += v * fast_rcp(1.f + fast_exp2(k + q));
}

// ---------------- fused prep: x cast + weight pack + bias concat ----------------
__global__ void prep_kernel(const float* __restrict__ x, unsigned short* __restrict__ xb,
                            const float* __restrict__ w1k, const float* __restrict__ b1k,
                            const float* __restrict__ w1q, const float* __restrict__ b1q,
                            const float* __restrict__ w1v, const float* __restrict__ b1v,
                            const float* __restrict__ w1s, const float* __restrict__ b1s,
                            const float* __restrict__ w2k, const float* __restrict__ b2k,
                            const float* __restrict__ w2q, const float* __restrict__ b2q,
                            const float* __restrict__ w2v, const float* __restrict__ b2v,
                            const float* __restrict__ w2s, const float* __restrict__ b2s,
                            unsigned short* __restrict__ BP1, float* __restrict__ bc1,
                            unsigned short* __restrict__ BP2, float* __restrict__ bc2) {
    int id = blockIdx.x * 256 + threadIdx.x;
    if (id < 800000) {
        float4 v0 = *(const float4*)&x[(size_t)id * 8];
        float4 v1 = *(const float4*)&x[(size_t)id * 8 + 4];
        short8v o;
        o[0] = (short)f2bf(v0.x); o[1] = (short)f2bf(v0.y);
        o[2] = (short)f2bf(v0.z); o[3] = (short)f2bf(v0.w);
        o[4] = (short)f2bf(v1.x); o[5] = (short)f2bf(v1.y);
        o[6] = (short)f2bf(v1.z); o[7] = (short)f2bf(v1.w);
        *(short8v*)(xb + (size_t)id * 8) = o;
    } else if (id < 808192) {
        int t = id - 800000;
        int l = t & 63, ks = (t >> 6) & 3, ct = t >> 8;
        int c = ct * 16 + (l & 15);
        int g = c >> 7, n = c & 127;
        const float* W = (g == 0) ? w1k : (g == 1) ? w1q : (g == 2) ? w1v : w1s;
        int kb = ks * 32 + ((l >> 4) << 3);
        short8v o;
#pragma unroll
        for (int j = 0; j < 8; ++j) o[j] = (short)f2bf(W[n * 128 + kb + j]);
        *(short8v*)(BP1 + (size_t)t * 8) = o;
    } else if (id < 812288) {
        int t = id - 808192;
        int l = t & 63, ks = (t >> 6) & 3, ct = t >> 8;
        int c = ct * 16 + (l & 15);
        int g = c >> 6, n = c & 63;
        const float* W = (g == 0) ? w2k : (g == 1) ? w2q : (g == 2) ? w2v : w2s;
        int kb = ks * 32 + ((l >> 4) << 3);
        short8v o;
#pragma unroll
        for (int j = 0; j < 8; ++j) o[j] = (short)f2bf(W[n * 128 + kb + j]);
        *(short8v*)(BP2 + (size_t)t * 8) = o;
    } else if (id < 812800) {
        int t = id - 812288;
        int g = t >> 7, n = t & 127;
        const float* B = (g == 0) ? b1k : (g == 1) ? b1q : (g == 2) ? b1v : b1s;
        bc1[t] = B[n];
    } else if (id < 813056) {
        int t = id - 812800;
        int g = t >> 6, n = t & 63;
        const float* B = (g == 0) ? b2k : (g == 1) ? b2q : (g == 2) ? b2v : b2s;
        bc2[t] = B[n];
    }
}

// ---------------- CSR build (plain dst buckets) ----------------
__global__ void hist_kernel(const int* __restrict__ dst, int* __restrict__ hist) {
    int e = blockIdx.x * 256 + threadIdx.x;
    if (e < N_EDGES) atomicAdd(&hist[dst[e]], 1);
}

__global__ void bsum_kernel(const int* __restrict__ hist, int* __restrict__ bsum) {
    int t = threadIdx.x;
    int idx = blockIdx.x * 256 + t;
    __shared__ int sh[256];
    sh[t] = (idx < N_NODES) ? hist[idx] : 0;
    __syncthreads();
    for (int d = 128; d > 0; d >>= 1) {
        if (t < d) sh[t] += sh[t + d];
        __syncthreads();
    }
    if (t == 0) bsum[blockIdx.x] = sh[0];
}

__global__ void bscan_kernel(const int* __restrict__ bsum, int* __restrict__ bbase) {
    int t = threadIdx.x;   // 256
    __shared__ int sh[256];
    sh[t] = (t < SCAN_BLOCKS) ? bsum[t] : 0;
    __syncthreads();
    for (int d = 1; d < 256; d <<= 1) {
        int v = (t >= d) ? sh[t - d] : 0;
        __syncthreads();
        sh[t] += v;
        __syncthreads();
    }
    if (t < SCAN_BLOCKS) bbase[t] = (t == 0) ? 0 : sh[t - 1];
}

__global__ void offs_kernel(const int* __restrict__ hist, const int* __restrict__ bbase,
                            int* __restrict__ offs, int* __restrict__ cursor) {
    int t = threadIdx.x;
    int idx = blockIdx.x * 256 + t;
    int v = (idx < N_NODES) ? hist[idx] : 0;
    __shared__ int sh[256];
    sh[t] = v;
    __syncthreads();
    for (int d = 1; d < 256; d <<= 1) {
        int u = (t >= d) ? sh[t - d] : 0;
        __syncthreads();
        sh[t] += u;
        __syncthreads();
    }
    if (idx < N_NODES) {
        int o = bbase[blockIdx.x] + sh[t] - v;   // exclusive
        offs[idx] = o;
        cursor[idx] = o;                          // cursor aliases hist: per-index RAW only
    }
    if (idx == 0) offs[N_NODES] = N_EDGES;
}

__global__ void fill_kernel(const int* __restrict__ src, const int* __restrict__ dst,
                            int* __restrict__ cursor, int* __restrict__ esrc) {
    int e = blockIdx.x * 256 + threadIdx.x;
    if (e < N_EDGES) {
        int d = dst[e];
        int pos = atomicAdd(&cursor[d], 1);
        esrc[pos] = src[e];
    }
}

// ---------------- bf16 MFMA GEMM with split epilogue (all outputs bf16) ----------------
// K and Q outputs pre-scaled by -log2e.
template <int LAYER>
__global__ __launch_bounds__(256) void gemm_mfma(const unsigned short* __restrict__ Ab,
                                                 const unsigned short* __restrict__ Bp,
                                                 const float* __restrict__ bias,
                                                 unsigned short* __restrict__ Kout,
                                                 unsigned short* __restrict__ Sout,
                                                 unsigned short* __restrict__ QVout,
                                                 int M) {
    __shared__ __align__(16) unsigned char As[32768];
    const int tid = threadIdx.x;
    const int w = tid >> 6, l = tid & 63;
    const int lx = l & 15, lg = l >> 4;
    const int row0 = blockIdx.x * 128;
    const int colb = blockIdx.y * 128;

#pragma unroll
    for (int i = 0; i < 8; ++i) {
        int id = i * 256 + tid;
        int r = id >> 4, c = id & 15;
        int gr = row0 + r;
        short8v v;
#pragma unroll
        for (int j = 0; j < 8; ++j) v[j] = 0;
        if (gr < M) v = *(const short8v*)(Ab + (size_t)gr * 128 + c * 8);
        *(short8v*)(As + r * 256 + ((c ^ (r & 7)) << 4)) = v;
    }
    __syncthreads();

    float4v acc[2][8];
#pragma unroll
    for (int m = 0; m < 2; ++m)
#pragma unroll
        for (int n = 0; n < 8; ++n)
#pragma unroll
            for (int q = 0; q < 4; ++q) acc[m][n][q] = 0.f;

    const int ct0 = blockIdx.y * 8;
#pragma unroll
    for (int ks = 0; ks < 4; ++ks) {
        short8v a[2];
#pragma unroll
        for (int m = 0; m < 2; ++m) {
            int rl = 32 * w + 16 * m + lx;
            int cc = ks * 4 + lg;
            a[m] = *(const short8v*)(As + rl * 256 + ((cc ^ (rl & 7)) << 4));
        }
#pragma unroll
        for (int n = 0; n < 8; ++n) {
            short8v b = *(const short8v*)(Bp + (size_t)(((ct0 + n) * 4 + ks) * 64 + l) * 8);
            acc[0][n] = __builtin_amdgcn_mfma_f32_16x16x32_bf16(a[0], b, acc[0][n], 0, 0, 0);
            acc[1][n] = __builtin_amdgcn_mfma_f32_16x16x32_bf16(a[1], b, acc[1][n], 0, 0, 0);
        }
    }

    float bb[8];
#pragma unroll
    for (int n = 0; n < 8; ++n) bb[n] = bias[colb + 16 * n + lx];

    const int rbase = row0 + 32 * w + 4 * lg;
#pragma unroll
    for (int m = 0; m < 2; ++m) {
#pragma unroll
        for (int reg = 0; reg < 4; ++reg) {
            int r = rbase + 16 * m + reg;
            if (r >= M) continue;
#pragma unroll
            for (int n = 0; n < 8; ++n) {
                float val = acc[m][n][reg] + bb[n];
                int c = 16 * n + lx;
                if (LAYER == 1) {
                    if (blockIdx.y == 0)      Kout[(size_t)r * 128 + c] = f2bf(-NLOG2E * val);
                    else if (blockIdx.y == 1) QVout[(size_t)r * 256 + 2 * c]     = f2bf(-NLOG2E * val);
                    else if (blockIdx.y == 2) QVout[(size_t)r * 256 + 2 * c + 1] = f2bf(val);
                    else                      Sout[(size_t)r * 128 + c] = f2bf(val);
                } else {
                    if (blockIdx.y == 0) {
                        if (c < 64) Kout[(size_t)r * 64 + c] = f2bf(-NLOG2E * val);
                        else        QVout[(size_t)r * 128 + 2 * (c - 64)] = f2bf(-NLOG2E * val);
                    } else {
                        if (c < 64) QVout[(size_t)r * 128 + 2 * c + 1] = f2bf(val);
                        else        Sout[(size_t)r * 64 + (c - 64)] = f2bf(val);
                    }
                }
            }
        }
    }
}

// ---------------- edge aggregation (gather, scalar loop, unroll-4 MLP) ----------------
__global__ __launch_bounds__(256) void edge1_kernel(const unsigned short* __restrict__ K1b,
                                                    const unsigned short* __restrict__ S1b,
                                                    const unsigned int* __restrict__ QV,
                                                    const int* __restrict__ offs,
                                                    const int* __restrict__ esrc,
                                                    unsigned short* __restrict__ H1B) {
    int node = __builtin_amdgcn_readfirstlane(blockIdx.x * 4 + (threadIdx.x >> 6));
    int lane = threadIdx.x & 63;
    unsigned int kr = *(const unsigned int*)(K1b + (size_t)node * 128 + lane * 2);
    unsigned int sr = *(const unsigned int*)(S1b + (size_t)node * 128 + lane * 2);
    float kx = u2f(kr << 16), ky = u2f(kr & 0xffff0000u);
    float sx = u2f(sr << 16), sy = u2f(sr & 0xffff0000u);
    float ax0 = 0.f, ay0 = 0.f, ax1 = 0.f, ay1 = 0.f;
    float ax2 = 0.f, ay2 = 0.f, ax3 = 0.f, ay3 = 0.f;
    int e0 = offs[node], e1 = offs[node + 1];
    int j = e0;
    for (; j + 4 <= e1; j += 4) {
        int s0 = esrc[j], s1 = esrc[j + 1], s2 = esrc[j + 2], s3 = esrc[j + 3];
        uint2 a = *(const uint2*)(QV + (size_t)s0 * 128 + lane * 2);
        uint2 b = *(const uint2*)(QV + (size_t)s1 * 128 + lane * 2);
        uint2 c = *(const uint2*)(QV + (size_t)s2 * 128 + lane * 2);
        uint2 d = *(const uint2*)(QV + (size_t)s3 * 128 + lane * 2);
        gacc2(a, kx, ky, ax0, ay0);
        gacc2(b, kx, ky, ax1, ay1);
        gacc2(c, kx, ky, ax2, ay2);
        gacc2(d, kx, ky, ax3, ay3);
    }
    for (; j < e1; ++j) {
        uint2 a = *(const uint2*)(QV + (size_t)esrc[j] * 128 + lane * 2);
        gacc2(a, kx, ky, ax0, ay0);
    }
    float rx = sx + (ax0 + ax1) + (ax2 + ax3);
    float ry = sy + (ay0 + ay1) + (ay2 + ay3);
    ushort2 o;
    o.x = f2bf(rx > 0.f ? rx : 0.f);
    o.y = f2bf(ry > 0.f ? ry : 0.f);
    *(ushort2*)(H1B + (size_t)node * 128 + lane * 2) = o;
}

__global__ __launch_bounds__(256) void edge2_kernel(const unsigned short* __restrict__ K2b,
                                                    const unsigned short* __restrict__ S2b,
                                                    const unsigned int* __restrict__ QV,
                                                    const int* __restrict__ offs,
                                                    const int* __restrict__ esrc,
                                                    float* __restrict__ H2) {
    int node = __builtin_amdgcn_readfirstlane(blockIdx.x * 4 + (threadIdx.x >> 6));
    int lane = threadIdx.x & 63;
    float k1 = u2f(((unsigned int)K2b[(size_t)node * 64 + lane]) << 16);
    float s1 = u2f(((unsigned int)S2b[(size_t)node * 64 + lane]) << 16);
    float a0 = 0.f, a1 = 0.f, a2 = 0.f, a3 = 0.f;
    int e0 = offs[node], e1 = offs[node + 1];
    int j = e0;
    for (; j + 4 <= e1; j += 4) {
        unsigned int qa = QV[(size_t)esrc[j] * 64 + lane];
        unsigned int qb = QV[(size_t)esrc[j + 1] * 64 + lane];
        unsigned int qc = QV[(size_t)esrc[j + 2] * 64 + lane];
        unsigned int qd = QV[(size_t)esrc[j + 3] * 64 + lane];
        gacc1(qa, k1, a0);
        gacc1(qb, k1, a1);
        gacc1(qc, k1, a2);
        gacc1(qd, k1, a3);
    }
    for (; j < e1; ++j) gacc1(QV[(size_t)esrc[j] * 64 + lane], k1, a0);
    float r = s1 + (a0 + a1) + (a2 + a3);
    H2[(size_t)node * 64 + lane] = r > 0.f ? r : 0.f;
}

// ---------------- pooling: wide partial sums (segmented by sorted batch) ----------------
__global__ void poolsum_kernel(const float* __restrict__ H2, const int* __restrict__ batch,
                               float* __restrict__ sums) {
    int start = blockIdx.x * 196;
    int end = start + 196;
    if (end > N_NODES) end = N_NODES;
    int ch = threadIdx.x & 63, sub = threadIdx.x >> 6;
    float acc = 0.f;
    int gcur = -1;
    for (int n = start + sub; n < end; n += 4) {
        int b = batch[n];
        if (b != gcur) {
            if (gcur >= 0) atomicAdd(&sums[gcur * 64 + ch], acc);
            gcur = b;
            acc = 0.f;
        }
        acc += H2[(size_t)n * 64 + ch];
    }
    if (gcur >= 0) atomicAdd(&sums[gcur * 64 + ch], acc);
}

// ---------------- fc: per-graph count via binary search, scale, dot ----------------
__global__ void fc_kernel(const float* __restrict__ sums, const int* __restrict__ batch,
                          const float* __restrict__ wfc, const float* __restrict__ bfc,
                          float* __restrict__ out) {
    int t = threadIdx.x;          // 128
    int g = t >> 1, c = t & 1;
    int lo = 0, hi = N_NODES;
    while (lo < hi) { int mid = (lo + hi) >> 1; if (batch[mid] < g) lo = mid + 1; else hi = mid; }
    int s = lo;
    hi = N_NODES;
    while (lo < hi) { int mid = (lo + hi) >> 1; if (batch[mid] <= g) lo = mid + 1; else hi = mid; }
    int cnt = lo - s;
    if (cnt < 1) cnt = 1;
    float inv = 1.f / (float)cnt;
    float sacc = bfc[c];
#pragma unroll
    for (int i = 0; i < 64; ++i) sacc += sums[g * 64 + i] * inv * wfc[c * 64 + i];
    out[g * 2 + c] = sacc;
}

// ---------------- launch ----------------
extern "C" void kernel_launch(void* const* d_in, const int* in_sizes, int n_in,
                              void* d_out, int out_size, void* d_ws, size_t ws_size,
                              hipStream_t stream) {
    (void)in_sizes; (void)n_in; (void)out_size; (void)ws_size;
    const float* x    = (const float*)d_in[0];
    const int*   ei   = (const int*)d_in[1];
    const int*   batch= (const int*)d_in[2];
    const float* w1k = (const float*)d_in[3];  const float* b1k = (const float*)d_in[4];
    const float* w1q = (const float*)d_in[5];  const float* b1q = (const float*)d_in[6];
    const float* w1v = (const float*)d_in[7];  const float* b1v = (const float*)d_in[8];
    const float* w1s = (const float*)d_in[9];  const float* b1s = (const float*)d_in[10];
    const float* w2k = (const float*)d_in[11]; const float* b2k = (const float*)d_in[12];
    const float* w2q = (const float*)d_in[13]; const float* b2q = (const float*)d_in[14];
    const float* w2v = (const float*)d_in[15]; const float* b2v = (const float*)d_in[16];
    const float* w2s = (const float*)d_in[17]; const float* b2s = (const float*)d_in[18];
    const float* wfc = (const float*)d_in[19]; const float* bfc = (const float*)d_in[20];
    float* out = (float*)d_out;

    char* ws = (char*)d_ws;
    unsigned short* K1  = (unsigned short*)(ws + OFF_K1);
    unsigned short* S1  = (unsigned short*)(ws + OFF_S1);
    unsigned short* QV1 = (unsigned short*)(ws + OFF_QV1);
    unsigned short* H1B = (unsigned short*)(ws + OFF_H1B);
    unsigned short* XB  = (unsigned short*)(ws + OFF_XB);
    unsigned short* K2  = (unsigned short*)(ws + OFF_K2);
    unsigned short* S2  = (unsigned short*)(ws + OFF_S2);
    unsigned short* QV2 = (unsigned short*)(ws + OFF_QV2);
    float* H2   = (float*)(ws + OFF_H2);
    int*   esrc = (int*)(ws + OFF_ESRC);
    int*   offs = (int*)(ws + OFF_OFFS);
    int*   curs = (int*)(ws + OFF_CURS);
    int*   bsum = (int*)(ws + OFF_BSUM);
    int*   bbas = (int*)(ws + OFF_BBAS);
    unsigned short* BP1 = (unsigned short*)(ws + OFF_BP1);
    float* bc1  = (float*)(ws + OFF_BC1);
    unsigned short* BP2 = (unsigned short*)(ws + OFF_BP2);
    float* bc2  = (float*)(ws + OFF_BC2);
    float* psum = (float*)(ws + OFF_PSUM);

    const int* src = ei;
    const int* dst = ei + N_EDGES;

    // fused prep: cast + weight pack + bias concat
    prep_kernel<<<3177, 256, 0, stream>>>(x, XB,
                                          w1k, b1k, w1q, b1q, w1v, b1v, w1s, b1s,
                                          w2k, b2k, w2q, b2q, w2v, b2v, w2s, b2s,
                                          BP1, bc1, BP2, bc2);

    // CSR build (by dst), hierarchical scan
    hipMemsetAsync(curs, 0, N_NODES * sizeof(int), stream);
    hipMemsetAsync(psum, 0, N_GRAPHS * 64 * sizeof(float), stream);
    hist_kernel<<<(N_EDGES + 255) / 256, 256, 0, stream>>>(dst, curs);
    bsum_kernel<<<SCAN_BLOCKS, 256, 0, stream>>>(curs, bsum);
    bscan_kernel<<<1, 256, 0, stream>>>(bsum, bbas);
    offs_kernel<<<SCAN_BLOCKS, 256, 0, stream>>>(curs, bbas, offs, curs);
    fill_kernel<<<(N_EDGES + 255) / 256, 256, 0, stream>>>(src, dst, curs, esrc);

    // layer 1
    gemm_mfma<1><<<dim3(391, 4), 256, 0, stream>>>(XB, BP1, bc1, K1, S1, QV1, N_NODES);
    edge1_kernel<<<12500, 256, 0, stream>>>(K1, S1, (const unsigned int*)QV1, offs, esrc, H1B);

    // layer 2
    gemm_mfma<2><<<dim3(391, 2), 256, 0, stream>>>(H1B, BP2, bc2, K2, S2, QV2, N_NODES);
    edge2_kernel<<<12500, 256, 0, stream>>>(K2, S2, (const unsigned int*)QV2, offs, esrc, H2);

    // pooling (wide partial sums) + fc
    poolsum_kernel<<<256, 256, 0, stream>>>(H2, batch, psum);
    fc_kernel<<<1, 128, 0, stream>>>(psum, batch, wfc, bfc, out);
}